// Round 6
// baseline (667.375 us; speedup 1.0000x reference)
//
#include <hip/hip_runtime.h>
#include <math.h>

#define TT 2048
#define DD 768
#define NN 256
#define NHH 12
#define BB 2
#define CH 512           // attention chunk (4 chunks of 4 x 128-tiles)

typedef unsigned short u16;
typedef __attribute__((ext_vector_type(8))) short bf16x8;
typedef __attribute__((ext_vector_type(8))) unsigned short u16x8;
typedef __attribute__((ext_vector_type(4))) float f32x4;

static inline int imin(int a, int b) { return a < b ? a : b; }

__device__ __forceinline__ u16 f2b(float f) {
  union { float f; unsigned u; } a; a.f = f;
  unsigned r = a.u + 0x7FFF + ((a.u >> 16) & 1);
  return (u16)(r >> 16);
}
__device__ __forceinline__ float b2f(u16 h) {
  union { unsigned u; float f; } a; a.u = ((unsigned)h) << 16;
  return a.f;
}

__device__ __forceinline__ void async16(const void* g, void* l) {
  __builtin_amdgcn_global_load_lds(
      (const __attribute__((address_space(1))) unsigned*)g,
      (__attribute__((address_space(3))) unsigned*)l, 16, 0, 0);
}

// Stage a 128x32 bf16 tile (row-major, ld in elements) into LDS [128][32].
__device__ __forceinline__ void stage128x32(
    const u16* __restrict__ gbase, size_t ld, u16* lds, int tid) {
  const int w = tid >> 6, l = tid & 63;
  const int r = l >> 2, kc = (l & 3) << 3;
#pragma unroll
  for (int q = 0; q < 2; ++q) {
    const int row0 = w * 32 + q * 16;
    async16(gbase + (size_t)(row0 + r) * ld + kc, lds + row0 * 32);
  }
}

// 16 MFMAs of one BK=32 step; wave (wr,wc) computes 64x64 of the 128x128 tile.
__device__ __forceinline__ void mfma_step(
    const u16* As, const u16* Bs, int wr, int wc, int lane, f32x4 acc[4][4]) {
  const int m16 = lane & 15, quad = lane >> 4;
  bf16x8 a[4], b[4];
#pragma unroll
  for (int i = 0; i < 4; ++i)
    a[i] = *(const bf16x8*)&As[(wr * 64 + i * 16 + m16) * 32 + quad * 8];
#pragma unroll
  for (int j = 0; j < 4; ++j)
    b[j] = *(const bf16x8*)&Bs[(wc * 64 + j * 16 + m16) * 32 + quad * 8];
#pragma unroll
  for (int i = 0; i < 4; ++i)
#pragma unroll
    for (int j = 0; j < 4; ++j)
      acc[i][j] = __builtin_amdgcn_mfma_f32_16x16x32_bf16(a[i], b[j], acc[i][j], 0, 0, 0);
}

// copy a 64x128 u16 tile from LDS (row-major, no pad) to global rows of ld.
__device__ __forceinline__ void copy_out64(
    const u16* buf, u16* g, size_t ld, int tid) {
#pragma unroll
  for (int s = 0; s < 4; ++s) {
    const int off = (s * 256 + tid) * 8;
    const int row = off >> 7, col = off & 127;
    *(u16x8*)&g[(size_t)row * ld + col] = *(const u16x8*)&buf[off];
  }
}

#define GEMM_PROLOGUE()                                            \
  __shared__ __attribute__((aligned(16))) u16 smem[8192];          \
  u16* As = smem;                                                  \
  u16* Bs = smem + 4096;                                           \
  const int tid = threadIdx.x;                                     \
  const int w = tid >> 6, lane = tid & 63;                         \
  const int wr = w >> 1, wc = w & 1;                               \
  const int col16 = lane & 15, quad = lane >> 4;                   \
  f32x4 acc[4][4];                                                 \
  _Pragma("unroll") for (int i = 0; i < 4; ++i)                    \
  _Pragma("unroll") for (int j = 0; j < 4; ++j)                    \
      acc[i][j] = (f32x4){0.f, 0.f, 0.f, 0.f};

// ---------------------------------------------------------------------------
__global__ __launch_bounds__(256) void cvt_bf16(
    const float* __restrict__ in, u16* __restrict__ out, size_t n4) {
  size_t i = ((size_t)blockIdx.x * 256 + threadIdx.x) * 4;
  if (i >= n4 * 4) return;
  float4 v = *(const float4*)&in[i];
  u16 o[4] = {f2b(v.x), f2b(v.y), f2b(v.z), f2b(v.w)};
  *(ushort4*)&out[i] = *(ushort4*)o;
}

__global__ __launch_bounds__(256) void tcvt_bf16(
    const float* __restrict__ in, u16* __restrict__ out, int R, int C,
    size_t inStride, size_t outStride) {
  __shared__ float tile[32][33];
  const float* ip = in + (size_t)blockIdx.z * inStride;
  u16* op = out + (size_t)blockIdx.z * outStride;
  const int c0 = blockIdx.x * 32, r0 = blockIdx.y * 32;
  const int tx = threadIdx.x & 31, ty = threadIdx.x >> 5;
#pragma unroll
  for (int p = 0; p < 4; ++p)
    tile[ty + p * 8][tx] = ip[(size_t)(r0 + ty + p * 8) * C + c0 + tx];
  __syncthreads();
#pragma unroll
  for (int p = 0; p < 4; ++p)
    op[(size_t)(c0 + ty + p * 8) * R + r0 + tx] = f2b(tile[tx][ty + p * 8]);
}

__global__ __launch_bounds__(256) void k_colsum(
    const u16* __restrict__ encvt, float* __restrict__ colsum) {
  const int row = blockIdx.x * 4 + (threadIdx.x >> 6);
  const int lane = threadIdx.x & 63;
  const u16* pr = encvt + (size_t)row * DD;
  float s = 0.f;
#pragma unroll
  for (int i = 0; i < 3; ++i) {
    ushort4 v = *(const ushort4*)&pr[(lane << 2) + i * 256];
    s += b2f(v.x) + b2f(v.y) + b2f(v.z) + b2f(v.w);
  }
#pragma unroll
  for (int off = 32; off; off >>= 1) s += __shfl_xor(s, off);
  if (lane == 0) colsum[row] = s;
}

__global__ __launch_bounds__(256) void k_zero(
    float* __restrict__ htf, u16* __restrict__ ht16) {
  const size_t i = ((size_t)blockIdx.x * 256 + threadIdx.x) * 4;
  *(float4*)&htf[i] = make_float4(0.f, 0.f, 0.f, 0.f);
  u16 z[4] = {0, 0, 0, 0};
  *(ushort4*)&ht16[i] = *(ushort4*)z;
}

// ---------------------------------------------------------------------------
// K1: latent = X16 @ ENCT[h]^T; relu; rope -> QR16 [b][h][t][n] AND
// QRT16 [b][h][n][t].  M=4096, N=256, K=768 per head.
// ---------------------------------------------------------------------------
__global__ __launch_bounds__(256) void k1_encode(
    const u16* __restrict__ x16, const u16* __restrict__ enct,
    u16* __restrict__ qr16, u16* __restrict__ qrt16) {
  const int h = blockIdx.z;
  const int m0 = blockIdx.x * 128, n0 = blockIdx.y * 128;
  GEMM_PROLOGUE();
  for (int k0 = 0; k0 < DD; k0 += 32) {
    stage128x32(x16 + (size_t)m0 * DD + k0, DD, As, tid);
    stage128x32(enct + ((size_t)h * NN + n0) * DD + k0, DD, Bs, tid);
    __syncthreads();
    mfma_step(As, Bs, wr, wc, lane, acc);
    __syncthreads();
  }
#pragma unroll
  for (int p = 0; p < 2; ++p) {
    __syncthreads();
    if (wr == p) {
#pragma unroll
      for (int i = 0; i < 4; ++i)
#pragma unroll
        for (int j = 0; j < 4; ++j) {
          const int n = n0 + wc * 64 + j * 16 + col16;
          const int q = n & ~1;
          const float freq = exp2f((float)q * -0.0625f) * 0.15915494309189535f;
          float rv[4], pv[4];
#pragma unroll
          for (int r = 0; r < 4; ++r) rv[r] = fmaxf(acc[i][j][r], 0.f);
#pragma unroll
          for (int r = 0; r < 4; ++r) pv[r] = __shfl_xor(rv[r], 1);
#pragma unroll
          for (int r = 0; r < 4; ++r) {
            const int lr = i * 16 + quad * 4 + r;
            const int t = (m0 + p * 64 + lr) & (TT - 1);
            float phase = (float)t * freq;
            float ph = (phase - floorf(phase)) * 6.283185307179586f;
            float s = __sinf(ph), c = __cosf(ph);
            float o = (n & 1) ? (rv[r] * c + pv[r] * s) : (rv[r] * c - pv[r] * s);
            smem[lr * 128 + wc * 64 + j * 16 + col16] = f2b(o);
          }
        }
    }
    __syncthreads();
    const int m = m0 + p * 64;
    const int b = m >> 11, tb = m & (TT - 1);
    const size_t sl = (size_t)(b * NHH + h);
    copy_out64(smem, qr16 + (sl * TT + tb) * NN + n0, NN, tid);
    // transposed copy: QRT16[sl][n][t] = tile[t][n]
#pragma unroll
    for (int s = 0; s < 4; ++s) {
      const int off = (s * 256 + tid) * 8;
      const int nr = off >> 6, tc = off & 63;
      u16 vals[8];
#pragma unroll
      for (int k = 0; k < 8; ++k) vals[k] = smem[(tc + k) * 128 + nr];
      *(u16x8*)&qrt16[(sl * NN + n0 + nr) * TT + tb + tc] = *(u16x8*)vals;
    }
  }
}

// ---------------------------------------------------------------------------
// kS: block-diagonal band of S = QR QR^T (strict lower), 40 tiles/slice.
// SB (group-local) [gs][TT][CH], sc = s - 512*(t/512).
// ---------------------------------------------------------------------------
__global__ __launch_bounds__(256) void kS_band(
    const u16* __restrict__ qr16, u16* __restrict__ sb, int bh0) {
  const int z = blockIdx.y;                  // group-local slice
  const int bh = bh0 + z;
  const int cc = blockIdx.x / 10, rr = blockIdx.x % 10;
  int i = (int)((sqrtf(8.f * rr + 1.f) - 1.f) * 0.5f);
  while ((i + 1) * (i + 2) / 2 <= rr) ++i;
  while (i * (i + 1) / 2 > rr) --i;
  const int j = rr - i * (i + 1) / 2;
  const int t0 = (cc * 4 + i) * 128;
  const int s0 = cc * CH + j * 128;
  const u16* q = qr16 + (size_t)bh * TT * NN;
  GEMM_PROLOGUE();
  for (int k0 = 0; k0 < NN; k0 += 32) {
    stage128x32(q + (size_t)t0 * NN + k0, NN, As, tid);
    stage128x32(q + (size_t)s0 * NN + k0, NN, Bs, tid);
    __syncthreads();
    mfma_step(As, Bs, wr, wc, lane, acc);
    __syncthreads();
  }
  const bool diag = (i == j);
#pragma unroll
  for (int p = 0; p < 2; ++p) {
    __syncthreads();
    if (wr == p) {
#pragma unroll
      for (int ii = 0; ii < 4; ++ii)
#pragma unroll
        for (int jj = 0; jj < 4; ++jj) {
          const int s = s0 + wc * 64 + jj * 16 + col16;
#pragma unroll
          for (int r = 0; r < 4; ++r) {
            const int lr = ii * 16 + quad * 4 + r;
            const int t = t0 + p * 64 + lr;
            float v = acc[ii][jj][r];
            if (diag && s >= t) v = 0.f;
            smem[lr * 128 + wc * 64 + jj * 16 + col16] = f2b(v);
          }
        }
    }
    __syncthreads();
    copy_out64(smem, sb + ((size_t)z * TT + t0 + p * 64) * CH + j * 128, CH, tid);
  }
}

// ---------------------------------------------------------------------------
// kA: ykvc (chunk-local) = QR[t-tile] @ HT16^T (K=256, skipped for c=0)
//               + sum_{j<=it} SB tile @ XT16 (K=128 each).
// ---------------------------------------------------------------------------
__global__ __launch_bounds__(256) void kA_attn(
    const u16* __restrict__ qr16, const u16* __restrict__ ht16,
    const u16* __restrict__ sb, const u16* __restrict__ xt16,
    u16* __restrict__ ykvc, int c, int bh0) {
  const int z = blockIdx.z;                  // group-local slice
  const int bh = bh0 + z, b = bh / NHH;
  const int it = blockIdx.y;                 // t-tile within chunk (0..3)
  const int d0 = blockIdx.x * 128;
  const int t0 = c * CH + it * 128;
  GEMM_PROLOGUE();
  if (c > 0) {
    for (int k0 = 0; k0 < NN; k0 += 32) {
      stage128x32(qr16 + ((size_t)bh * TT + t0) * NN + k0, NN, As, tid);
      stage128x32(ht16 + ((size_t)z * DD + d0) * NN + k0, NN, Bs, tid);
      __syncthreads();
      mfma_step(As, Bs, wr, wc, lane, acc);
      __syncthreads();
    }
  }
  for (int j = 0; j <= it; ++j) {
    for (int k0 = 0; k0 < 128; k0 += 32) {
      stage128x32(sb + ((size_t)z * TT + t0) * CH + j * 128 + k0, CH, As, tid);
      stage128x32(xt16 + ((size_t)b * DD + d0) * TT + c * CH + j * 128 + k0, TT, Bs, tid);
      __syncthreads();
      mfma_step(As, Bs, wr, wc, lane, acc);
      __syncthreads();
    }
  }
#pragma unroll
  for (int p = 0; p < 2; ++p) {
    __syncthreads();
    if (wr == p) {
#pragma unroll
      for (int i = 0; i < 4; ++i)
#pragma unroll
        for (int j = 0; j < 4; ++j)
#pragma unroll
          for (int r = 0; r < 4; ++r) {
            const int lr = i * 16 + quad * 4 + r;
            smem[lr * 128 + wc * 64 + j * 16 + col16] = f2b(acc[i][j][r]);
          }
    }
    __syncthreads();
    copy_out64(smem, ykvc + ((size_t)z * CH + it * 128 + p * 64) * DD + d0, DD, tid);
  }
}

// ---------------------------------------------------------------------------
// kB: HTF[z][d][n] += XT16[b][d][chunk] @ QRT16[bh][n][chunk]^T (K=512);
// HT16 = bf16(HTF).  z group-local.
// ---------------------------------------------------------------------------
__global__ __launch_bounds__(256) void kB_state(
    const u16* __restrict__ xt16, const u16* __restrict__ qrt16,
    float* __restrict__ htf, u16* __restrict__ ht16, int c, int bh0) {
  const int z = blockIdx.z;
  const int bh = bh0 + z, b = bh / NHH;
  const int d0 = blockIdx.x * 128, n0 = blockIdx.y * 128;
  GEMM_PROLOGUE();
  for (int k0 = 0; k0 < CH; k0 += 32) {
    stage128x32(xt16 + ((size_t)b * DD + d0) * TT + c * CH + k0, TT, As, tid);
    stage128x32(qrt16 + ((size_t)bh * NN + n0) * TT + c * CH + k0, TT, Bs, tid);
    __syncthreads();
    mfma_step(As, Bs, wr, wc, lane, acc);
    __syncthreads();
  }
#pragma unroll
  for (int i = 0; i < 4; ++i)
#pragma unroll
    for (int j = 0; j < 4; ++j) {
      const int n = n0 + wc * 64 + j * 16 + col16;
#pragma unroll
      for (int r = 0; r < 4; ++r) {
        const int d = d0 + wr * 64 + i * 16 + quad * 4 + r;
        const size_t gi = ((size_t)z * DD + d) * NN + n;
        float f = htf[gi] + acc[i][j][r];
        htf[gi] = f;
        ht16[gi] = f2b(f);
      }
    }
}

// ---------------------------------------------------------------------------
// K3: per-row mean/rstd of chunk-local ykvc (bf16 rows of 768). 1 wave/row.
// ---------------------------------------------------------------------------
__global__ __launch_bounds__(256) void k3_stats(
    const u16* __restrict__ ykvc, float* __restrict__ mu, float* __restrict__ rs) {
  const int row = blockIdx.x * 4 + (threadIdx.x >> 6);
  const int lane = threadIdx.x & 63;
  const u16* p = ykvc + (size_t)row * DD;
  float sum = 0.f, sq = 0.f;
#pragma unroll
  for (int i = 0; i < 3; ++i) {
    ushort4 v = *(const ushort4*)&p[(lane << 2) + i * 256];
    float f0 = b2f(v.x), f1 = b2f(v.y), f2 = b2f(v.z), f3 = b2f(v.w);
    sum += f0 + f1 + f2 + f3;
    sq += f0 * f0 + f1 * f1 + f2 * f2 + f3 * f3;
  }
#pragma unroll
  for (int off = 32; off; off >>= 1) {
    sum += __shfl_xor(sum, off);
    sq += __shfl_xor(sq, off);
  }
  if (lane == 0) {
    float m = sum * (1.f / 768.f);
    float v = sq * (1.f / 768.f) - m * m;
    mu[row] = m;
    rs[row] = rsqrtf(v + 1e-5f);
  }
}

// ---------------------------------------------------------------------------
// K4: raw GEMM ykvc @ ENCVT[h]^T with LN as epilogue affine; xs via inverse
// rope of QR16; out2 = xs*ys (fp32) + XY16 (bf16). Chunk-local A.
// ---------------------------------------------------------------------------
__global__ __launch_bounds__(256) void k4_xy(
    const u16* __restrict__ ykvc, const u16* __restrict__ encvt,
    const u16* __restrict__ qr16, const float* __restrict__ mu,
    const float* __restrict__ rs, const float* __restrict__ colsum,
    float* __restrict__ out2, u16* __restrict__ xy16, int c, int bh0) {
  const int z = blockIdx.z;
  const int bh = bh0 + z, h = bh % NHH;
  const int tl0 = blockIdx.x * 128, n0 = blockIdx.y * 128;
  GEMM_PROLOGUE();
  for (int k0 = 0; k0 < DD; k0 += 32) {
    stage128x32(ykvc + ((size_t)z * CH + tl0) * DD + k0, DD, As, tid);
    stage128x32(encvt + ((size_t)h * NN + n0) * DD + k0, DD, Bs, tid);
    __syncthreads();
    mfma_step(As, Bs, wr, wc, lane, acc);
    __syncthreads();
  }
#pragma unroll
  for (int p = 0; p < 2; ++p) {
    __syncthreads();
    if (wr == p) {
#pragma unroll
      for (int i = 0; i < 4; ++i)
#pragma unroll
        for (int j = 0; j < 4; ++j) {
          const int n = n0 + wc * 64 + j * 16 + col16;
          const int qn = n & ~1;
          const float freq = exp2f((float)qn * -0.0625f) * 0.15915494309189535f;
          const float cs = colsum[h * NN + n];
#pragma unroll
          for (int r = 0; r < 4; ++r) {
            const int lr = i * 16 + quad * 4 + r;
            const int tl = tl0 + p * 64 + lr;        // chunk-local t
            const int t = c * CH + tl;               // global t
            const int lrow = z * CH + tl;
            const float muv = mu[lrow], rsv = rs[lrow];
            float ys = fmaxf(rsv * acc[i][j][r] - rsv * muv * cs, 0.f);
            const size_t gi = ((size_t)bh * TT + t) * NN + n;
            float qs = b2f(qr16[gi]);
            float qp = b2f(qr16[gi ^ 1]);
            float phase = (float)t * freq;
            float ph = (phase - floorf(phase)) * 6.283185307179586f;
            float s = __sinf(ph), c2 = __cosf(ph);
            float xs = (n & 1) ? (qs * c2 - qp * s) : (qs * c2 + qp * s);
            float val = ys * xs;
            out2[gi] = val;
            smem[lr * 128 + wc * 64 + j * 16 + col16] = f2b(val);
          }
        }
    }
    __syncthreads();
    copy_out64(smem, xy16 + ((size_t)bh * TT + c * CH + tl0 + p * 64) * NN + n0,
               NN, tid);
  }
}

// ---------------------------------------------------------------------------
// K5: ymlp = flat(XY16) @ DECT^T.  M=4096, N=768, K=3072.
// ---------------------------------------------------------------------------
__global__ __launch_bounds__(256) void k5_mlp(
    const u16* __restrict__ xy16, const u16* __restrict__ dect,
    float* __restrict__ ymlp) {
  const int m0 = blockIdx.x * 128, d0 = blockIdx.y * 128;
  GEMM_PROLOGUE();
  for (int k0 = 0; k0 < NHH * NN; k0 += 32) {
    {  // gather-stage A
      const int l = tid & 63;
      const int hh = k0 >> 8, kk = (k0 & 255) + ((l & 3) << 3);
#pragma unroll
      for (int q = 0; q < 2; ++q) {
        const int row0 = w * 32 + q * 16;
        const int m = m0 + row0 + (l >> 2);
        const int b = m >> 11, t = m & (TT - 1);
        async16(xy16 + ((size_t)(b * NHH + hh) * TT + t) * NN + kk,
                As + row0 * 32);
      }
    }
    stage128x32(dect + (size_t)d0 * (NHH * NN) + k0, NHH * NN, Bs, tid);
    __syncthreads();
    mfma_step(As, Bs, wr, wc, lane, acc);
    __syncthreads();
  }
#pragma unroll
  for (int i = 0; i < 4; ++i)
#pragma unroll
    for (int j = 0; j < 4; ++j) {
      const int d = d0 + wc * 64 + j * 16 + col16;
#pragma unroll
      for (int r = 0; r < 4; ++r) {
        const int m = m0 + wr * 64 + i * 16 + quad * 4 + r;
        ymlp[(size_t)m * DD + d] = acc[i][j][r];
      }
    }
}

// ---------------------------------------------------------------------------
// K6: y = ln(ymlp)*sqrt(0.1/(ra+1e-6))*scale; out1 = ln(x+y). Block per row.
// ---------------------------------------------------------------------------
__global__ __launch_bounds__(256) void k6_final(
    const float* __restrict__ ymlp, const float* __restrict__ x,
    const float* __restrict__ scale, const float* __restrict__ ra,
    float* __restrict__ out1) {
  const int row = blockIdx.x;
  const int tid = threadIdx.x;
  const int wid = tid >> 6, lane = tid & 63;
  __shared__ float red[8];
  float v[3];
  float sum = 0.f, sq = 0.f;
#pragma unroll
  for (int j = 0; j < 3; ++j) {
    v[j] = ymlp[(size_t)row * DD + tid + j * 256];
    sum += v[j]; sq += v[j] * v[j];
  }
#pragma unroll
  for (int off = 32; off; off >>= 1) { sum += __shfl_xor(sum, off); sq += __shfl_xor(sq, off); }
  if (lane == 0) { red[wid] = sum; red[4 + wid] = sq; }
  __syncthreads();
  sum = red[0] + red[1] + red[2] + red[3];
  sq = red[4] + red[5] + red[6] + red[7];
  const float m1 = sum * (1.f / 768.f);
  const float r1 = rsqrtf(sq * (1.f / 768.f) - m1 * m1 + 1e-5f);
  float z[3];
  float sum2 = 0.f, sq2 = 0.f;
#pragma unroll
  for (int j = 0; j < 3; ++j) {
    const int d = tid + j * 256;
    float y = (v[j] - m1) * r1 * sqrtf(0.1f / (ra[d] + 1e-6f)) * scale[d];
    z[j] = x[(size_t)row * DD + d] + y;
    sum2 += z[j]; sq2 += z[j] * z[j];
  }
  __syncthreads();
#pragma unroll
  for (int off = 32; off; off >>= 1) { sum2 += __shfl_xor(sum2, off); sq2 += __shfl_xor(sq2, off); }
  if (lane == 0) { red[wid] = sum2; red[4 + wid] = sq2; }
  __syncthreads();
  sum2 = red[0] + red[1] + red[2] + red[3];
  sq2 = red[4] + red[5] + red[6] + red[7];
  const float m2 = sum2 * (1.f / 768.f);
  const float r2 = rsqrtf(sq2 * (1.f / 768.f) - m2 * m2 + 1e-5f);
#pragma unroll
  for (int j = 0; j < 3; ++j)
    out1[(size_t)row * DD + tid + j * 256] = (z[j] - m2) * r2;
}

// ---------------------------------------------------------------------------
extern "C" void kernel_launch(void* const* d_in, const int* in_sizes, int n_in,
                              void* d_out, int out_size, void* d_ws, size_t ws_size,
                              hipStream_t stream) {
  const float* x = (const float*)d_in[0];
  const float* enc = (const float*)d_in[1];
  const float* encv = (const float*)d_in[2];
  const float* dec = (const float*)d_in[3];
  const float* scale = (const float*)d_in[4];
  const float* ra = (const float*)d_in[5];
  float* out1 = (float*)d_out;
  float* out2 = out1 + (size_t)BB * TT * DD;

  const int NS = BB * NHH;  // 24 slices
  unsigned char* p = (unsigned char*)d_ws;
  u16* X16 = (u16*)p;    p += (size_t)BB * TT * DD * 2;
  u16* XT16 = (u16*)p;   p += (size_t)BB * DD * TT * 2;
  u16* ENCT = (u16*)p;   p += (size_t)NHH * NN * DD * 2;
  u16* ENCVT = (u16*)p;  p += (size_t)NHH * NN * DD * 2;
  u16* DECT = (u16*)p;   p += (size_t)DD * NHH * NN * 2;
  u16* QR16 = (u16*)p;   p += (size_t)NS * TT * NN * 2;
  u16* QRT16 = (u16*)p;  p += (size_t)NS * NN * TT * 2;
  u16* XY16 = (u16*)p;   p += (size_t)NS * TT * NN * 2;
  float* COLSUM = (float*)p; p += (size_t)NHH * NN * 4;
  float* ymlp = (float*)p;   p += (size_t)BB * TT * DD * 4;
  // Adaptive per-slice attention pool:
  //   SB (TT*CH bf16) + HTF (DD*NN f32) + HT16 (DD*NN bf16) +
  //   YKVC (CH*DD bf16) + MU/RS (CH f32 each)
  const size_t SLICE_B = (size_t)TT * CH * 2 + (size_t)DD * NN * 4 +
                         (size_t)DD * NN * 2 + (size_t)CH * DD * 2 +
                         (size_t)CH * 8;
  size_t fixed = (size_t)(p - (unsigned char*)d_ws);
  size_t rem = (ws_size > fixed) ? ws_size - fixed : 0;
  int GS = (int)(rem / SLICE_B);
  if (GS < 1) GS = 1;
  if (GS > NS) GS = NS;
  u16* SB = (u16*)p;         p += (size_t)GS * TT * CH * 2;
  float* HTF = (float*)p;    p += (size_t)GS * DD * NN * 4;
  u16* HT16 = (u16*)p;       p += (size_t)GS * DD * NN * 2;
  u16* YKVC = (u16*)p;       p += (size_t)GS * CH * DD * 2;
  float* MU = (float*)p;     p += (size_t)GS * CH * 4;
  float* RS = (float*)p;     p += (size_t)GS * CH * 4;

  // One-time conversions / transposes
  cvt_bf16<<<dim3((BB * TT * DD) / 1024), 256, 0, stream>>>(x, X16, (size_t)BB * TT * DD / 4);
  tcvt_bf16<<<dim3(DD / 32, TT / 32, BB), 256, 0, stream>>>(
      x, XT16, TT, DD, (size_t)TT * DD, (size_t)DD * TT);
  tcvt_bf16<<<dim3(NN / 32, DD / 32, NHH), 256, 0, stream>>>(
      enc, ENCT, DD, NN, (size_t)DD * NN, (size_t)NN * DD);
  tcvt_bf16<<<dim3(NN / 32, DD / 32, NHH), 256, 0, stream>>>(
      encv, ENCVT, DD, NN, (size_t)DD * NN, (size_t)NN * DD);
  tcvt_bf16<<<dim3(DD / 32, (NHH * NN) / 32, 1), 256, 0, stream>>>(
      dec, DECT, NHH * NN, DD, 0, 0);
  k_colsum<<<dim3(NHH * NN / 4), 256, 0, stream>>>(ENCVT, COLSUM);

  k1_encode<<<dim3(BB * TT / 128, NN / 128, NHH), 256, 0, stream>>>(
      X16, ENCT, QR16, QRT16);

  for (int bh0 = 0; bh0 < NS; bh0 += GS) {
    const int gs = imin(GS, NS - bh0);
    kS_band<<<dim3(40, gs), 256, 0, stream>>>(QR16, SB, bh0);
    k_zero<<<dim3(gs * DD * NN / 1024), 256, 0, stream>>>(HTF, HT16);
    for (int c = 0; c < TT / CH; ++c) {
      kA_attn<<<dim3(DD / 128, CH / 128, gs), 256, 0, stream>>>(
          QR16, HT16, SB, XT16, YKVC, c, bh0);
      k3_stats<<<dim3(gs * CH / 4), 256, 0, stream>>>(YKVC, MU, RS);
      k4_xy<<<dim3(CH / 128, NN / 128, gs), 256, 0, stream>>>(
          YKVC, ENCVT, QR16, MU, RS, COLSUM, out2, XY16, c, bh0);
      if (c < TT / CH - 1)
        kB_state<<<dim3(DD / 128, NN / 128, gs), 256, 0, stream>>>(
            XT16, QRT16, HTF, HT16, c, bh0);
    }
  }

  k5_mlp<<<dim3(BB * TT / 128, DD / 128), 256, 0, stream>>>(XY16, DECT, ymlp);
  k6_final<<<dim3(BB * TT), 256, 0, stream>>>(ymlp, x, scale, ra, out1);
}

// Round 7
// 613.545 us; speedup vs baseline: 1.0877x; 1.0877x over previous
//
#include <hip/hip_runtime.h>
#include <math.h>

#define TT 2048
#define DD 768
#define NN 256
#define NHH 12
#define BB 2
#define CH 512           // attention chunk (4 chunks of 4 x 128-tiles)

typedef unsigned short u16;
typedef __attribute__((ext_vector_type(8))) short bf16x8;
typedef __attribute__((ext_vector_type(8))) unsigned short u16x8;
typedef __attribute__((ext_vector_type(4))) float f32x4;

static inline int imin(int a, int b) { return a < b ? a : b; }

__device__ __forceinline__ u16 f2b(float f) {
  union { float f; unsigned u; } a; a.f = f;
  unsigned r = a.u + 0x7FFF + ((a.u >> 16) & 1);
  return (u16)(r >> 16);
}
__device__ __forceinline__ float b2f(u16 h) {
  union { unsigned u; float f; } a; a.u = ((unsigned)h) << 16;
  return a.f;
}

__device__ __forceinline__ void async16(const void* g, void* l) {
  __builtin_amdgcn_global_load_lds(
      (const __attribute__((address_space(1))) unsigned*)g,
      (__attribute__((address_space(3))) unsigned*)l, 16, 0, 0);
}

// Stage a 128x32 bf16 tile (row-major, ld in elements) into LDS [128][32].
__device__ __forceinline__ void stage128x32(
    const u16* __restrict__ gbase, size_t ld, u16* lds, int tid) {
  const int w = tid >> 6, l = tid & 63;
  const int r = l >> 2, kc = (l & 3) << 3;
#pragma unroll
  for (int q = 0; q < 2; ++q) {
    const int row0 = w * 32 + q * 16;
    async16(gbase + (size_t)(row0 + r) * ld + kc, lds + row0 * 32);
  }
}

// Stage a 64x32 bf16 tile into LDS [64][32]. One async16 per thread.
__device__ __forceinline__ void stage64x32(
    const u16* __restrict__ gbase, size_t ld, u16* lds, int tid) {
  const int w = tid >> 6, l = tid & 63;
  const int r = w * 16 + (l >> 2), kc = (l & 3) << 3;
  async16(gbase + (size_t)r * ld + kc, lds + w * 512);
}

// 16 MFMAs of one BK=32 step; wave (wr,wc) computes 64x64 of the 128x128 tile.
__device__ __forceinline__ void mfma_step(
    const u16* As, const u16* Bs, int wr, int wc, int lane, f32x4 acc[4][4]) {
  const int m16 = lane & 15, quad = lane >> 4;
  bf16x8 a[4], b[4];
#pragma unroll
  for (int i = 0; i < 4; ++i)
    a[i] = *(const bf16x8*)&As[(wr * 64 + i * 16 + m16) * 32 + quad * 8];
#pragma unroll
  for (int j = 0; j < 4; ++j)
    b[j] = *(const bf16x8*)&Bs[(wc * 64 + j * 16 + m16) * 32 + quad * 8];
#pragma unroll
  for (int i = 0; i < 4; ++i)
#pragma unroll
    for (int j = 0; j < 4; ++j)
      acc[i][j] = __builtin_amdgcn_mfma_f32_16x16x32_bf16(a[i], b[j], acc[i][j], 0, 0, 0);
}

// copy a 64x128 u16 tile from LDS (row-major, no pad) to global rows of ld.
__device__ __forceinline__ void copy_out64(
    const u16* buf, u16* g, size_t ld, int tid) {
#pragma unroll
  for (int s = 0; s < 4; ++s) {
    const int off = (s * 256 + tid) * 8;
    const int row = off >> 7, col = off & 127;
    *(u16x8*)&g[(size_t)row * ld + col] = *(const u16x8*)&buf[off];
  }
}

#define GEMM_PROLOGUE()                                            \
  __shared__ __attribute__((aligned(16))) u16 smem[8192];          \
  u16* As = smem;                                                  \
  u16* Bs = smem + 4096;                                           \
  const int tid = threadIdx.x;                                     \
  const int w = tid >> 6, lane = tid & 63;                         \
  const int wr = w >> 1, wc = w & 1;                               \
  const int col16 = lane & 15, quad = lane >> 4;                   \
  f32x4 acc[4][4];                                                 \
  _Pragma("unroll") for (int i = 0; i < 4; ++i)                    \
  _Pragma("unroll") for (int j = 0; j < 4; ++j)                    \
      acc[i][j] = (f32x4){0.f, 0.f, 0.f, 0.f};

// ---------------------------------------------------------------------------
__global__ __launch_bounds__(256) void cvt_bf16(
    const float* __restrict__ in, u16* __restrict__ out, size_t n4) {
  size_t i = ((size_t)blockIdx.x * 256 + threadIdx.x) * 4;
  if (i >= n4 * 4) return;
  float4 v = *(const float4*)&in[i];
  u16 o[4] = {f2b(v.x), f2b(v.y), f2b(v.z), f2b(v.w)};
  *(ushort4*)&out[i] = *(ushort4*)o;
}

__global__ __launch_bounds__(256) void tcvt_bf16(
    const float* __restrict__ in, u16* __restrict__ out, int R, int C,
    size_t inStride, size_t outStride) {
  __shared__ float tile[32][33];
  const float* ip = in + (size_t)blockIdx.z * inStride;
  u16* op = out + (size_t)blockIdx.z * outStride;
  const int c0 = blockIdx.x * 32, r0 = blockIdx.y * 32;
  const int tx = threadIdx.x & 31, ty = threadIdx.x >> 5;
#pragma unroll
  for (int p = 0; p < 4; ++p)
    tile[ty + p * 8][tx] = ip[(size_t)(r0 + ty + p * 8) * C + c0 + tx];
  __syncthreads();
#pragma unroll
  for (int p = 0; p < 4; ++p)
    op[(size_t)(c0 + ty + p * 8) * R + r0 + tx] = f2b(tile[tx][ty + p * 8]);
}

__global__ __launch_bounds__(256) void k_colsum(
    const u16* __restrict__ encvt, float* __restrict__ colsum) {
  const int row = blockIdx.x * 4 + (threadIdx.x >> 6);
  const int lane = threadIdx.x & 63;
  const u16* pr = encvt + (size_t)row * DD;
  float s = 0.f;
#pragma unroll
  for (int i = 0; i < 3; ++i) {
    ushort4 v = *(const ushort4*)&pr[(lane << 2) + i * 256];
    s += b2f(v.x) + b2f(v.y) + b2f(v.z) + b2f(v.w);
  }
#pragma unroll
  for (int off = 32; off; off >>= 1) s += __shfl_xor(s, off);
  if (lane == 0) colsum[row] = s;
}

// ---------------------------------------------------------------------------
// K1: latent = X16 @ ENCT[h]^T; relu; rope -> QR16 [b][h][t][n] AND
// QRT16 [b][h][n][t].  M=4096, N=256, K=768 per head.
// ---------------------------------------------------------------------------
__global__ __launch_bounds__(256) void k1_encode(
    const u16* __restrict__ x16, const u16* __restrict__ enct,
    u16* __restrict__ qr16, u16* __restrict__ qrt16) {
  const int h = blockIdx.z;
  const int m0 = blockIdx.x * 128, n0 = blockIdx.y * 128;
  GEMM_PROLOGUE();
  for (int k0 = 0; k0 < DD; k0 += 32) {
    stage128x32(x16 + (size_t)m0 * DD + k0, DD, As, tid);
    stage128x32(enct + ((size_t)h * NN + n0) * DD + k0, DD, Bs, tid);
    __syncthreads();
    mfma_step(As, Bs, wr, wc, lane, acc);
    __syncthreads();
  }
#pragma unroll
  for (int p = 0; p < 2; ++p) {
    __syncthreads();
    if (wr == p) {
#pragma unroll
      for (int i = 0; i < 4; ++i)
#pragma unroll
        for (int j = 0; j < 4; ++j) {
          const int n = n0 + wc * 64 + j * 16 + col16;
          const int q = n & ~1;
          const float freq = exp2f((float)q * -0.0625f) * 0.15915494309189535f;
          float rv[4], pv[4];
#pragma unroll
          for (int r = 0; r < 4; ++r) rv[r] = fmaxf(acc[i][j][r], 0.f);
#pragma unroll
          for (int r = 0; r < 4; ++r) pv[r] = __shfl_xor(rv[r], 1);
#pragma unroll
          for (int r = 0; r < 4; ++r) {
            const int lr = i * 16 + quad * 4 + r;
            const int t = (m0 + p * 64 + lr) & (TT - 1);
            float phase = (float)t * freq;
            float ph = (phase - floorf(phase)) * 6.283185307179586f;
            float s = __sinf(ph), c = __cosf(ph);
            float o = (n & 1) ? (rv[r] * c + pv[r] * s) : (rv[r] * c - pv[r] * s);
            smem[lr * 128 + wc * 64 + j * 16 + col16] = f2b(o);
          }
        }
    }
    __syncthreads();
    const int m = m0 + p * 64;
    const int b = m >> 11, tb = m & (TT - 1);
    const size_t sl = (size_t)(b * NHH + h);
    copy_out64(smem, qr16 + (sl * TT + tb) * NN + n0, NN, tid);
    // transposed copy: QRT16[sl][n][t] = tile[t][n]
#pragma unroll
    for (int s = 0; s < 4; ++s) {
      const int off = (s * 256 + tid) * 8;
      const int nr = off >> 6, tc = off & 63;
      u16 vals[8];
#pragma unroll
      for (int k = 0; k < 8; ++k) vals[k] = smem[(tc + k) * 128 + nr];
      *(u16x8*)&qrt16[(sl * NN + n0 + nr) * TT + tb + tc] = *(u16x8*)vals;
    }
  }
}

// ---------------------------------------------------------------------------
// kS: block-diagonal band of S = QR QR^T (strict lower), 40 tiles/slice.
// SB (group-local) [gs][TT][CH], sc = s - 512*(t/512).
// ---------------------------------------------------------------------------
__global__ __launch_bounds__(256) void kS_band(
    const u16* __restrict__ qr16, u16* __restrict__ sb, int bh0) {
  const int z = blockIdx.y;                  // group-local slice
  const int bh = bh0 + z;
  const int cc = blockIdx.x / 10, rr = blockIdx.x % 10;
  int i = (int)((sqrtf(8.f * rr + 1.f) - 1.f) * 0.5f);
  while ((i + 1) * (i + 2) / 2 <= rr) ++i;
  while (i * (i + 1) / 2 > rr) --i;
  const int j = rr - i * (i + 1) / 2;
  const int t0 = (cc * 4 + i) * 128;
  const int s0 = cc * CH + j * 128;
  const u16* q = qr16 + (size_t)bh * TT * NN;
  GEMM_PROLOGUE();
  for (int k0 = 0; k0 < NN; k0 += 32) {
    stage128x32(q + (size_t)t0 * NN + k0, NN, As, tid);
    stage128x32(q + (size_t)s0 * NN + k0, NN, Bs, tid);
    __syncthreads();
    mfma_step(As, Bs, wr, wc, lane, acc);
    __syncthreads();
  }
  const bool diag = (i == j);
#pragma unroll
  for (int p = 0; p < 2; ++p) {
    __syncthreads();
    if (wr == p) {
#pragma unroll
      for (int ii = 0; ii < 4; ++ii)
#pragma unroll
        for (int jj = 0; jj < 4; ++jj) {
          const int s = s0 + wc * 64 + jj * 16 + col16;
#pragma unroll
          for (int r = 0; r < 4; ++r) {
            const int lr = ii * 16 + quad * 4 + r;
            const int t = t0 + p * 64 + lr;
            float v = acc[ii][jj][r];
            if (diag && s >= t) v = 0.f;
            smem[lr * 128 + wc * 64 + jj * 16 + col16] = f2b(v);
          }
        }
    }
    __syncthreads();
    copy_out64(smem, sb + ((size_t)z * TT + t0 + p * 64) * CH + j * 128, CH, tid);
  }
}

// ---------------------------------------------------------------------------
// kB: P_c = XT16[b][:, chunk c] @ QRT16[bh][:, chunk c]^T (K=512);
// H16[z][c] = bf16( H16[z][c-1] + P_c )  (snapshot prefix, c=0..2).
// Coalesced store via LDS restage; prev-snapshot add at copy time.
// ---------------------------------------------------------------------------
__global__ __launch_bounds__(256) void kB_state(
    const u16* __restrict__ xt16, const u16* __restrict__ qrt16,
    u16* __restrict__ h16, int c, int bh0) {
  const int z = blockIdx.z;
  const int bh = bh0 + z, b = bh / NHH;
  const int d0 = blockIdx.x * 128, n0 = blockIdx.y * 128;
  GEMM_PROLOGUE();
  for (int k0 = 0; k0 < CH; k0 += 32) {
    stage128x32(xt16 + ((size_t)b * DD + d0) * TT + c * CH + k0, TT, As, tid);
    stage128x32(qrt16 + ((size_t)bh * NN + n0) * TT + c * CH + k0, TT, Bs, tid);
    __syncthreads();
    mfma_step(As, Bs, wr, wc, lane, acc);
    __syncthreads();
  }
  u16* hnext = h16 + (size_t)(z * 3 + c) * DD * NN;
  const u16* hprev = h16 + (size_t)(z * 3 + c - 1) * DD * NN;
#pragma unroll
  for (int p = 0; p < 2; ++p) {
    __syncthreads();
    if (wr == p) {
#pragma unroll
      for (int i = 0; i < 4; ++i)
#pragma unroll
        for (int j = 0; j < 4; ++j)
#pragma unroll
          for (int r = 0; r < 4; ++r) {
            const int lr = i * 16 + quad * 4 + r;
            smem[lr * 128 + wc * 64 + j * 16 + col16] = f2b(acc[i][j][r]);
          }
    }
    __syncthreads();
#pragma unroll
    for (int s = 0; s < 4; ++s) {
      const int off = (s * 256 + tid) * 8;
      const int row = off >> 7, col = off & 127;
      const size_t gi = (size_t)(d0 + p * 64 + row) * NN + n0 + col;
      u16x8 cur = *(const u16x8*)&smem[off];
      if (c > 0) {
        u16x8 prev = *(const u16x8*)&hprev[gi];
#pragma unroll
        for (int k = 0; k < 8; ++k) cur[k] = f2b(b2f(cur[k]) + b2f(prev[k]));
      }
      *(u16x8*)&hnext[gi] = cur;
    }
  }
}

// ---------------------------------------------------------------------------
// kA: one launch for all 16 t-tiles. yKV tile =
//     QR[t-tile] @ H16[z][c-1]^T (K=256, skipped for c=0)
//   + sum_{j<=it} SB tile @ XT16 (K=128 each), c = tt/4, it = tt%4.
// ---------------------------------------------------------------------------
__global__ __launch_bounds__(256) void kA_attn(
    const u16* __restrict__ qr16, const u16* __restrict__ h16,
    const u16* __restrict__ sb, const u16* __restrict__ xt16,
    u16* __restrict__ ykv16, int bh0) {
  const int z = blockIdx.z;
  const int bh = bh0 + z, b = bh / NHH;
  const int tt = blockIdx.y;                 // global t-tile 0..15
  const int c = tt >> 2, it = tt & 3;
  const int d0 = blockIdx.x * 128;
  const int t0 = tt * 128;
  GEMM_PROLOGUE();
  if (c > 0) {
    const u16* hs = h16 + ((size_t)(z * 3 + c - 1) * DD + d0) * NN;
    for (int k0 = 0; k0 < NN; k0 += 32) {
      stage128x32(qr16 + ((size_t)bh * TT + t0) * NN + k0, NN, As, tid);
      stage128x32(hs + k0, NN, Bs, tid);
      __syncthreads();
      mfma_step(As, Bs, wr, wc, lane, acc);
      __syncthreads();
    }
  }
  for (int j = 0; j <= it; ++j) {
    for (int k0 = 0; k0 < 128; k0 += 32) {
      stage128x32(sb + ((size_t)z * TT + t0) * CH + j * 128 + k0, CH, As, tid);
      stage128x32(xt16 + ((size_t)b * DD + d0) * TT + c * CH + j * 128 + k0, TT, Bs, tid);
      __syncthreads();
      mfma_step(As, Bs, wr, wc, lane, acc);
      __syncthreads();
    }
  }
#pragma unroll
  for (int p = 0; p < 2; ++p) {
    __syncthreads();
    if (wr == p) {
#pragma unroll
      for (int i = 0; i < 4; ++i)
#pragma unroll
        for (int j = 0; j < 4; ++j)
#pragma unroll
          for (int r = 0; r < 4; ++r) {
            const int lr = i * 16 + quad * 4 + r;
            smem[lr * 128 + wc * 64 + j * 16 + col16] = f2b(acc[i][j][r]);
          }
    }
    __syncthreads();
    copy_out64(smem, ykv16 + ((size_t)z * TT + t0 + p * 64) * DD + d0, DD, tid);
  }
}

// ---------------------------------------------------------------------------
// K3: per-row mean/rstd of group-local ykv16 (bf16 rows of 768). 1 wave/row.
// ---------------------------------------------------------------------------
__global__ __launch_bounds__(256) void k3_stats(
    const u16* __restrict__ ykv16, float* __restrict__ mu, float* __restrict__ rs) {
  const int row = blockIdx.x * 4 + (threadIdx.x >> 6);
  const int lane = threadIdx.x & 63;
  const u16* p = ykv16 + (size_t)row * DD;
  float sum = 0.f, sq = 0.f;
#pragma unroll
  for (int i = 0; i < 3; ++i) {
    ushort4 v = *(const ushort4*)&p[(lane << 2) + i * 256];
    float f0 = b2f(v.x), f1 = b2f(v.y), f2 = b2f(v.z), f3 = b2f(v.w);
    sum += f0 + f1 + f2 + f3;
    sq += f0 * f0 + f1 * f1 + f2 * f2 + f3 * f3;
  }
#pragma unroll
  for (int off = 32; off; off >>= 1) {
    sum += __shfl_xor(sum, off);
    sq += __shfl_xor(sq, off);
  }
  if (lane == 0) {
    float m = sum * (1.f / 768.f);
    float v = sq * (1.f / 768.f) - m * m;
    mu[row] = m;
    rs[row] = rsqrtf(v + 1e-5f);
  }
}

// ---------------------------------------------------------------------------
// K4: raw GEMM ykv16 @ ENCVT[h]^T with LN as epilogue affine; xs via inverse
// rope of QR16; out2 = xs*ys (fp32, [b][h][t][n]) + XYF (bf16, flat [m][3072]).
// ---------------------------------------------------------------------------
__global__ __launch_bounds__(256) void k4_xy(
    const u16* __restrict__ ykv16, const u16* __restrict__ encvt,
    const u16* __restrict__ qr16, const float* __restrict__ mu,
    const float* __restrict__ rs, const float* __restrict__ colsum,
    float* __restrict__ out2, u16* __restrict__ xyf, int bh0) {
  const int z = blockIdx.z;
  const int bh = bh0 + z, h = bh % NHH, b = bh / NHH;
  const int t0 = blockIdx.x * 128, n0 = blockIdx.y * 128;
  GEMM_PROLOGUE();
  for (int k0 = 0; k0 < DD; k0 += 32) {
    stage128x32(ykv16 + ((size_t)z * TT + t0) * DD + k0, DD, As, tid);
    stage128x32(encvt + ((size_t)h * NN + n0) * DD + k0, DD, Bs, tid);
    __syncthreads();
    mfma_step(As, Bs, wr, wc, lane, acc);
    __syncthreads();
  }
#pragma unroll
  for (int p = 0; p < 2; ++p) {
    __syncthreads();
    if (wr == p) {
#pragma unroll
      for (int i = 0; i < 4; ++i)
#pragma unroll
        for (int j = 0; j < 4; ++j) {
          const int n = n0 + wc * 64 + j * 16 + col16;
          const int qn = n & ~1;
          const float freq = exp2f((float)qn * -0.0625f) * 0.15915494309189535f;
          const float cs = colsum[h * NN + n];
#pragma unroll
          for (int r = 0; r < 4; ++r) {
            const int lr = i * 16 + quad * 4 + r;
            const int t = t0 + p * 64 + lr;
            const int lrow = z * TT + t;
            const float muv = mu[lrow], rsv = rs[lrow];
            float ys = fmaxf(rsv * acc[i][j][r] - rsv * muv * cs, 0.f);
            const size_t gi = ((size_t)bh * TT + t) * NN + n;
            float qs = b2f(qr16[gi]);
            float qp = b2f(qr16[gi ^ 1]);
            float phase = (float)t * freq;
            float ph = (phase - floorf(phase)) * 6.283185307179586f;
            float s = __sinf(ph), c2 = __cosf(ph);
            float xs = (n & 1) ? (qs * c2 - qp * s) : (qs * c2 + qp * s);
            float val = ys * xs;
            out2[gi] = val;
            smem[lr * 128 + wc * 64 + j * 16 + col16] = f2b(val);
          }
        }
    }
    __syncthreads();
    copy_out64(smem,
               xyf + ((size_t)(b * TT + t0 + p * 64)) * (NHH * NN) + h * NN + n0,
               NHH * NN, tid);
  }
}

// ---------------------------------------------------------------------------
// K5: ymlp = XYF @ DECT^T.  M=4096, N=768, K=3072.  64x64 tiles for
// occupancy (grid 64x12 = 768 blocks); plain contiguous A staging.
// ---------------------------------------------------------------------------
__global__ __launch_bounds__(256) void k5_mlp(
    const u16* __restrict__ xyf, const u16* __restrict__ dect,
    float* __restrict__ ymlp) {
  __shared__ __attribute__((aligned(16))) u16 sm[4096];
  u16* As = sm;
  u16* Bs = sm + 2048;
  const int tid = threadIdx.x;
  const int w = tid >> 6, lane = tid & 63;
  const int wr = w >> 1, wc = w & 1;
  const int m16 = lane & 15, quad = lane >> 4;
  const int m0 = blockIdx.x * 64, d0 = blockIdx.y * 64;
  f32x4 acc[2][2];
#pragma unroll
  for (int i = 0; i < 2; ++i)
#pragma unroll
    for (int j = 0; j < 2; ++j) acc[i][j] = (f32x4){0.f, 0.f, 0.f, 0.f};
  for (int k0 = 0; k0 < NHH * NN; k0 += 32) {
    stage64x32(xyf + (size_t)m0 * (NHH * NN) + k0, NHH * NN, As, tid);
    stage64x32(dect + (size_t)d0 * (NHH * NN) + k0, NHH * NN, Bs, tid);
    __syncthreads();
    bf16x8 a[2], b[2];
#pragma unroll
    for (int i = 0; i < 2; ++i)
      a[i] = *(const bf16x8*)&As[(wr * 32 + i * 16 + m16) * 32 + quad * 8];
#pragma unroll
    for (int j = 0; j < 2; ++j)
      b[j] = *(const bf16x8*)&Bs[(wc * 32 + j * 16 + m16) * 32 + quad * 8];
#pragma unroll
    for (int i = 0; i < 2; ++i)
#pragma unroll
      for (int j = 0; j < 2; ++j)
        acc[i][j] = __builtin_amdgcn_mfma_f32_16x16x32_bf16(a[i], b[j], acc[i][j], 0, 0, 0);
    __syncthreads();
  }
#pragma unroll
  for (int i = 0; i < 2; ++i)
#pragma unroll
    for (int j = 0; j < 2; ++j) {
      const int d = d0 + wc * 32 + j * 16 + m16;
#pragma unroll
      for (int r = 0; r < 4; ++r) {
        const int m = m0 + wr * 32 + i * 16 + quad * 4 + r;
        ymlp[(size_t)m * DD + d] = acc[i][j][r];
      }
    }
}

// ---------------------------------------------------------------------------
// K6: y = ln(ymlp)*sqrt(0.1/(ra+1e-6))*scale; out1 = ln(x+y). Block per row.
// ---------------------------------------------------------------------------
__global__ __launch_bounds__(256) void k6_final(
    const float* __restrict__ ymlp, const float* __restrict__ x,
    const float* __restrict__ scale, const float* __restrict__ ra,
    float* __restrict__ out1) {
  const int row = blockIdx.x;
  const int tid = threadIdx.x;
  const int wid = tid >> 6, lane = tid & 63;
  __shared__ float red[8];
  float v[3];
  float sum = 0.f, sq = 0.f;
#pragma unroll
  for (int j = 0; j < 3; ++j) {
    v[j] = ymlp[(size_t)row * DD + tid + j * 256];
    sum += v[j]; sq += v[j] * v[j];
  }
#pragma unroll
  for (int off = 32; off; off >>= 1) { sum += __shfl_xor(sum, off); sq += __shfl_xor(sq, off); }
  if (lane == 0) { red[wid] = sum; red[4 + wid] = sq; }
  __syncthreads();
  sum = red[0] + red[1] + red[2] + red[3];
  sq = red[4] + red[5] + red[6] + red[7];
  const float m1 = sum * (1.f / 768.f);
  const float r1 = rsqrtf(sq * (1.f / 768.f) - m1 * m1 + 1e-5f);
  float z[3];
  float sum2 = 0.f, sq2 = 0.f;
#pragma unroll
  for (int j = 0; j < 3; ++j) {
    const int d = tid + j * 256;
    float y = (v[j] - m1) * r1 * sqrtf(0.1f / (ra[d] + 1e-6f)) * scale[d];
    z[j] = x[(size_t)row * DD + d] + y;
    sum2 += z[j]; sq2 += z[j] * z[j];
  }
  __syncthreads();
#pragma unroll
  for (int off = 32; off; off >>= 1) { sum2 += __shfl_xor(sum2, off); sq2 += __shfl_xor(sq2, off); }
  if (lane == 0) { red[wid] = sum2; red[4 + wid] = sq2; }
  __syncthreads();
  sum2 = red[0] + red[1] + red[2] + red[3];
  sq2 = red[4] + red[5] + red[6] + red[7];
  const float m2 = sum2 * (1.f / 768.f);
  const float r2 = rsqrtf(sq2 * (1.f / 768.f) - m2 * m2 + 1e-5f);
#pragma unroll
  for (int j = 0; j < 3; ++j)
    out1[(size_t)row * DD + tid + j * 256] = (z[j] - m2) * r2;
}

// ---------------------------------------------------------------------------
extern "C" void kernel_launch(void* const* d_in, const int* in_sizes, int n_in,
                              void* d_out, int out_size, void* d_ws, size_t ws_size,
                              hipStream_t stream) {
  const float* x = (const float*)d_in[0];
  const float* enc = (const float*)d_in[1];
  const float* encv = (const float*)d_in[2];
  const float* dec = (const float*)d_in[3];
  const float* scale = (const float*)d_in[4];
  const float* ra = (const float*)d_in[5];
  float* out1 = (float*)d_out;
  float* out2 = out1 + (size_t)BB * TT * DD;

  const int NS = BB * NHH;  // 24 slices
  unsigned char* p = (unsigned char*)d_ws;
  u16* X16 = (u16*)p;    p += (size_t)BB * TT * DD * 2;
  u16* XT16 = (u16*)p;   p += (size_t)BB * DD * TT * 2;
  u16* ENCT = (u16*)p;   p += (size_t)NHH * NN * DD * 2;
  u16* ENCVT = (u16*)p;  p += (size_t)NHH * NN * DD * 2;
  u16* DECT = (u16*)p;   p += (size_t)DD * NHH * NN * 2;
  u16* QR16 = (u16*)p;   p += (size_t)NS * TT * NN * 2;
  u16* QRT16 = (u16*)p;  p += (size_t)NS * NN * TT * 2;
  u16* XYF = (u16*)p;    p += (size_t)BB * TT * NHH * NN * 2;   // flat [m][3072]
  float* COLSUM = (float*)p; p += (size_t)NHH * NN * 4;
  float* ymlp = (float*)p;   p += (size_t)BB * TT * DD * 4;
  // Adaptive per-slice attention pool:
  //   SB (TT*CH bf16) + H16 (3 snapshots DD*NN bf16) + YKV16 (TT*DD bf16)
  //   + MU/RS (TT f32 each)
  const size_t SLICE_B = (size_t)TT * CH * 2 + 3 * (size_t)DD * NN * 2 +
                         (size_t)TT * DD * 2 + (size_t)TT * 8;
  size_t fixed = (size_t)(p - (unsigned char*)d_ws);
  size_t rem = (ws_size > fixed) ? ws_size - fixed : 0;
  int GS = (int)(rem / SLICE_B);
  if (GS < 1) GS = 1;
  if (GS > NS) GS = NS;
  u16* SB = (u16*)p;     p += (size_t)GS * TT * CH * 2;
  u16* H16 = (u16*)p;    p += (size_t)GS * 3 * DD * NN * 2;
  u16* YKV16 = (u16*)p;  p += (size_t)GS * TT * DD * 2;
  float* MU = (float*)p; p += (size_t)GS * TT * 4;
  float* RS = (float*)p; p += (size_t)GS * TT * 4;

  // One-time conversions / transposes
  cvt_bf16<<<dim3((BB * TT * DD) / 1024), 256, 0, stream>>>(x, X16, (size_t)BB * TT * DD / 4);
  tcvt_bf16<<<dim3(DD / 32, TT / 32, BB), 256, 0, stream>>>(
      x, XT16, TT, DD, (size_t)TT * DD, (size_t)DD * TT);
  tcvt_bf16<<<dim3(NN / 32, DD / 32, NHH), 256, 0, stream>>>(
      enc, ENCT, DD, NN, (size_t)DD * NN, (size_t)NN * DD);
  tcvt_bf16<<<dim3(NN / 32, DD / 32, NHH), 256, 0, stream>>>(
      encv, ENCVT, DD, NN, (size_t)DD * NN, (size_t)NN * DD);
  tcvt_bf16<<<dim3(DD / 32, (NHH * NN) / 32, 1), 256, 0, stream>>>(
      dec, DECT, NHH * NN, DD, 0, 0);
  k_colsum<<<dim3(NHH * NN / 4), 256, 0, stream>>>(ENCVT, COLSUM);

  k1_encode<<<dim3(BB * TT / 128, NN / 128, NHH), 256, 0, stream>>>(
      X16, ENCT, QR16, QRT16);

  for (int bh0 = 0; bh0 < NS; bh0 += GS) {
    const int gs = imin(GS, NS - bh0);
    kS_band<<<dim3(40, gs), 256, 0, stream>>>(QR16, SB, bh0);
    for (int c = 0; c < TT / CH - 1; ++c)
      kB_state<<<dim3(DD / 128, NN / 128, gs), 256, 0, stream>>>(
          XT16, QRT16, H16, c, bh0);
    kA_attn<<<dim3(DD / 128, TT / 128, gs), 256, 0, stream>>>(
        QR16, H16, SB, XT16, YKV16, bh0);
    k3_stats<<<dim3(gs * TT / 4), 256, 0, stream>>>(YKV16, MU, RS);
    k4_xy<<<dim3(TT / 128, NN / 128, gs), 256, 0, stream>>>(
        YKV16, ENCVT, QR16, MU, RS, COLSUM, out2, XYF, bh0);
  }

  k5_mlp<<<dim3(BB * TT / 64, DD / 64), 256, 0, stream>>>(XYF, DECT, ymlp);
  k6_final<<<dim3(BB * TT), 256, 0, stream>>>(ymlp, x, scale, ra, out1);
}

// Round 8
// 535.074 us; speedup vs baseline: 1.2473x; 1.1467x over previous
//
#include <hip/hip_runtime.h>
#include <math.h>

#define TT 2048
#define DD 768
#define NN 256
#define NHH 12
#define BB 2
#define CH 512           // attention chunk (4 chunks of 4 x 128-tiles)

typedef unsigned short u16;
typedef __attribute__((ext_vector_type(8))) short bf16x8;
typedef __attribute__((ext_vector_type(8))) unsigned short u16x8;
typedef __attribute__((ext_vector_type(4))) float f32x4;

static inline int imin(int a, int b) { return a < b ? a : b; }

__device__ __forceinline__ u16 f2b(float f) {
  union { float f; unsigned u; } a; a.f = f;
  unsigned r = a.u + 0x7FFF + ((a.u >> 16) & 1);
  return (u16)(r >> 16);
}
__device__ __forceinline__ float b2f(u16 h) {
  union { unsigned u; float f; } a; a.u = ((unsigned)h) << 16;
  return a.f;
}

__device__ __forceinline__ void async16(const void* g, void* l) {
  __builtin_amdgcn_global_load_lds(
      (const __attribute__((address_space(1))) unsigned*)g,
      (__attribute__((address_space(3))) unsigned*)l, 16, 0, 0);
}

// Stage a 128x32 bf16 tile (row-major, ld in elements) into LDS [128][32].
__device__ __forceinline__ void stage128x32(
    const u16* __restrict__ gbase, size_t ld, u16* lds, int tid) {
  const int w = tid >> 6, l = tid & 63;
  const int r = l >> 2, kc = (l & 3) << 3;
#pragma unroll
  for (int q = 0; q < 2; ++q) {
    const int row0 = w * 32 + q * 16;
    async16(gbase + (size_t)(row0 + r) * ld + kc, lds + row0 * 32);
  }
}

// Stage a 64x32 bf16 tile into LDS [64][32]. One async16 per thread.
__device__ __forceinline__ void stage64x32(
    const u16* __restrict__ gbase, size_t ld, u16* lds, int tid) {
  const int w = tid >> 6, l = tid & 63;
  const int r = w * 16 + (l >> 2), kc = (l & 3) << 3;
  async16(gbase + (size_t)r * ld + kc, lds + w * 512);
}

// 16 MFMAs of one BK=32 step; wave (wr,wc) computes 64x64 of the 128x128 tile.
__device__ __forceinline__ void mfma_step(
    const u16* As, const u16* Bs, int wr, int wc, int lane, f32x4 acc[4][4]) {
  const int m16 = lane & 15, quad = lane >> 4;
  bf16x8 a[4], b[4];
#pragma unroll
  for (int i = 0; i < 4; ++i)
    a[i] = *(const bf16x8*)&As[(wr * 64 + i * 16 + m16) * 32 + quad * 8];
#pragma unroll
  for (int j = 0; j < 4; ++j)
    b[j] = *(const bf16x8*)&Bs[(wc * 64 + j * 16 + m16) * 32 + quad * 8];
#pragma unroll
  for (int i = 0; i < 4; ++i)
#pragma unroll
    for (int j = 0; j < 4; ++j)
      acc[i][j] = __builtin_amdgcn_mfma_f32_16x16x32_bf16(a[i], b[j], acc[i][j], 0, 0, 0);
}

// copy a 64x128 u16 tile from LDS (row-major, no pad) to global rows of ld.
__device__ __forceinline__ void copy_out64(
    const u16* buf, u16* g, size_t ld, int tid) {
#pragma unroll
  for (int s = 0; s < 4; ++s) {
    const int off = (s * 256 + tid) * 8;
    const int row = off >> 7, col = off & 127;
    *(u16x8*)&g[(size_t)row * ld + col] = *(const u16x8*)&buf[off];
  }
}

#define GEMM_PROLOGUE()                                            \
  __shared__ __attribute__((aligned(16))) u16 smem[8192];          \
  u16* As = smem;                                                  \
  u16* Bs = smem + 4096;                                           \
  const int tid = threadIdx.x;                                     \
  const int w = tid >> 6, lane = tid & 63;                         \
  const int wr = w >> 1, wc = w & 1;                               \
  const int col16 = lane & 15, quad = lane >> 4;                   \
  f32x4 acc[4][4];                                                 \
  _Pragma("unroll") for (int i = 0; i < 4; ++i)                    \
  _Pragma("unroll") for (int j = 0; j < 4; ++j)                    \
      acc[i][j] = (f32x4){0.f, 0.f, 0.f, 0.f};

// ---------------------------------------------------------------------------
__global__ __launch_bounds__(256) void cvt_bf16(
    const float* __restrict__ in, u16* __restrict__ out, size_t n4) {
  size_t i = ((size_t)blockIdx.x * 256 + threadIdx.x) * 4;
  if (i >= n4 * 4) return;
  float4 v = *(const float4*)&in[i];
  u16 o[4] = {f2b(v.x), f2b(v.y), f2b(v.z), f2b(v.w)};
  *(ushort4*)&out[i] = *(ushort4*)o;
}

__global__ __launch_bounds__(256) void tcvt_bf16(
    const float* __restrict__ in, u16* __restrict__ out, int R, int C,
    size_t inStride, size_t outStride) {
  __shared__ float tile[32][33];
  const float* ip = in + (size_t)blockIdx.z * inStride;
  u16* op = out + (size_t)blockIdx.z * outStride;
  const int c0 = blockIdx.x * 32, r0 = blockIdx.y * 32;
  const int tx = threadIdx.x & 31, ty = threadIdx.x >> 5;
#pragma unroll
  for (int p = 0; p < 4; ++p)
    tile[ty + p * 8][tx] = ip[(size_t)(r0 + ty + p * 8) * C + c0 + tx];
  __syncthreads();
#pragma unroll
  for (int p = 0; p < 4; ++p)
    op[(size_t)(c0 + ty + p * 8) * R + r0 + tx] = f2b(tile[tx][ty + p * 8]);
}

__global__ __launch_bounds__(256) void k_colsum(
    const u16* __restrict__ encvt, float* __restrict__ colsum) {
  const int row = blockIdx.x * 4 + (threadIdx.x >> 6);
  const int lane = threadIdx.x & 63;
  const u16* pr = encvt + (size_t)row * DD;
  float s = 0.f;
#pragma unroll
  for (int i = 0; i < 3; ++i) {
    ushort4 v = *(const ushort4*)&pr[(lane << 2) + i * 256];
    s += b2f(v.x) + b2f(v.y) + b2f(v.z) + b2f(v.w);
  }
#pragma unroll
  for (int off = 32; off; off >>= 1) s += __shfl_xor(s, off);
  if (lane == 0) colsum[row] = s;
}

// ---------------------------------------------------------------------------
// K1: latent = X16 @ ENCT[h]^T; relu; rope -> QR16 [b][h][t][n] AND
// QRT16 [b][h][n][t].  M=4096, N=256, K=768 per head.
// ---------------------------------------------------------------------------
__global__ __launch_bounds__(256) void k1_encode(
    const u16* __restrict__ x16, const u16* __restrict__ enct,
    u16* __restrict__ qr16, u16* __restrict__ qrt16) {
  const int h = blockIdx.z;
  const int m0 = blockIdx.x * 128, n0 = blockIdx.y * 128;
  GEMM_PROLOGUE();
  for (int k0 = 0; k0 < DD; k0 += 32) {
    stage128x32(x16 + (size_t)m0 * DD + k0, DD, As, tid);
    stage128x32(enct + ((size_t)h * NN + n0) * DD + k0, DD, Bs, tid);
    __syncthreads();
    mfma_step(As, Bs, wr, wc, lane, acc);
    __syncthreads();
  }
#pragma unroll
  for (int p = 0; p < 2; ++p) {
    __syncthreads();
    if (wr == p) {
#pragma unroll
      for (int i = 0; i < 4; ++i)
#pragma unroll
        for (int j = 0; j < 4; ++j) {
          const int n = n0 + wc * 64 + j * 16 + col16;
          const int q = n & ~1;
          const float freq = exp2f((float)q * -0.0625f) * 0.15915494309189535f;
          float rv[4], pv[4];
#pragma unroll
          for (int r = 0; r < 4; ++r) rv[r] = fmaxf(acc[i][j][r], 0.f);
#pragma unroll
          for (int r = 0; r < 4; ++r) pv[r] = __shfl_xor(rv[r], 1);
#pragma unroll
          for (int r = 0; r < 4; ++r) {
            const int lr = i * 16 + quad * 4 + r;
            const int t = (m0 + p * 64 + lr) & (TT - 1);
            float phase = (float)t * freq;
            float ph = (phase - floorf(phase)) * 6.283185307179586f;
            float s = __sinf(ph), c = __cosf(ph);
            float o = (n & 1) ? (rv[r] * c + pv[r] * s) : (rv[r] * c - pv[r] * s);
            smem[lr * 128 + wc * 64 + j * 16 + col16] = f2b(o);
          }
        }
    }
    __syncthreads();
    const int m = m0 + p * 64;
    const int b = m >> 11, tb = m & (TT - 1);
    const size_t sl = (size_t)(b * NHH + h);
    copy_out64(smem, qr16 + (sl * TT + tb) * NN + n0, NN, tid);
    // transposed copy: QRT16[sl][n][t] = tile[t][n]
#pragma unroll
    for (int s = 0; s < 4; ++s) {
      const int off = (s * 256 + tid) * 8;
      const int nr = off >> 6, tc = off & 63;
      u16 vals[8];
#pragma unroll
      for (int k = 0; k < 8; ++k) vals[k] = smem[(tc + k) * 128 + nr];
      *(u16x8*)&qrt16[(sl * NN + n0 + nr) * TT + tb + tc] = *(u16x8*)vals;
    }
  }
}

// ---------------------------------------------------------------------------
// kS: block-diagonal band of S = QR QR^T (strict lower), 40 tiles/slice.
// SB (group-local) [gs][TT][CH], sc = s - 512*(t/512).
// ---------------------------------------------------------------------------
__global__ __launch_bounds__(256) void kS_band(
    const u16* __restrict__ qr16, u16* __restrict__ sb, int bh0) {
  const int z = blockIdx.y;                  // group-local slice
  const int bh = bh0 + z;
  const int cc = blockIdx.x / 10, rr = blockIdx.x % 10;
  int i = (int)((sqrtf(8.f * rr + 1.f) - 1.f) * 0.5f);
  while ((i + 1) * (i + 2) / 2 <= rr) ++i;
  while (i * (i + 1) / 2 > rr) --i;
  const int j = rr - i * (i + 1) / 2;
  const int t0 = (cc * 4 + i) * 128;
  const int s0 = cc * CH + j * 128;
  const u16* q = qr16 + (size_t)bh * TT * NN;
  GEMM_PROLOGUE();
  for (int k0 = 0; k0 < NN; k0 += 32) {
    stage128x32(q + (size_t)t0 * NN + k0, NN, As, tid);
    stage128x32(q + (size_t)s0 * NN + k0, NN, Bs, tid);
    __syncthreads();
    mfma_step(As, Bs, wr, wc, lane, acc);
    __syncthreads();
  }
  const bool diag = (i == j);
#pragma unroll
  for (int p = 0; p < 2; ++p) {
    __syncthreads();
    if (wr == p) {
#pragma unroll
      for (int ii = 0; ii < 4; ++ii)
#pragma unroll
        for (int jj = 0; jj < 4; ++jj) {
          const int s = s0 + wc * 64 + jj * 16 + col16;
#pragma unroll
          for (int r = 0; r < 4; ++r) {
            const int lr = ii * 16 + quad * 4 + r;
            const int t = t0 + p * 64 + lr;
            float v = acc[ii][jj][r];
            if (diag && s >= t) v = 0.f;
            smem[lr * 128 + wc * 64 + jj * 16 + col16] = f2b(v);
          }
        }
    }
    __syncthreads();
    copy_out64(smem, sb + ((size_t)z * TT + t0 + p * 64) * CH + j * 128, CH, tid);
  }
}

// ---------------------------------------------------------------------------
// kB: P_c = XT16[b][:, chunk c] @ QRT16[bh][:, chunk c]^T (K=512);
// H16[z][c] = bf16( H16[z][c-1] + P_c )  (snapshot prefix, c=0..2).
// ---------------------------------------------------------------------------
__global__ __launch_bounds__(256) void kB_state(
    const u16* __restrict__ xt16, const u16* __restrict__ qrt16,
    u16* __restrict__ h16, int c, int bh0) {
  const int z = blockIdx.z;
  const int bh = bh0 + z, b = bh / NHH;
  const int d0 = blockIdx.x * 128, n0 = blockIdx.y * 128;
  GEMM_PROLOGUE();
  for (int k0 = 0; k0 < CH; k0 += 32) {
    stage128x32(xt16 + ((size_t)b * DD + d0) * TT + c * CH + k0, TT, As, tid);
    stage128x32(qrt16 + ((size_t)bh * NN + n0) * TT + c * CH + k0, TT, Bs, tid);
    __syncthreads();
    mfma_step(As, Bs, wr, wc, lane, acc);
    __syncthreads();
  }
  u16* hnext = h16 + (size_t)(z * 3 + c) * DD * NN;
  const u16* hprev = h16 + (size_t)(z * 3 + c - 1) * DD * NN;
#pragma unroll
  for (int p = 0; p < 2; ++p) {
    __syncthreads();
    if (wr == p) {
#pragma unroll
      for (int i = 0; i < 4; ++i)
#pragma unroll
        for (int j = 0; j < 4; ++j)
#pragma unroll
          for (int r = 0; r < 4; ++r) {
            const int lr = i * 16 + quad * 4 + r;
            smem[lr * 128 + wc * 64 + j * 16 + col16] = f2b(acc[i][j][r]);
          }
    }
    __syncthreads();
#pragma unroll
    for (int s = 0; s < 4; ++s) {
      const int off = (s * 256 + tid) * 8;
      const int row = off >> 7, col = off & 127;
      const size_t gi = (size_t)(d0 + p * 64 + row) * NN + n0 + col;
      u16x8 cur = *(const u16x8*)&smem[off];
      if (c > 0) {
        u16x8 prev = *(const u16x8*)&hprev[gi];
#pragma unroll
        for (int k = 0; k < 8; ++k) cur[k] = f2b(b2f(cur[k]) + b2f(prev[k]));
      }
      *(u16x8*)&hnext[gi] = cur;
    }
  }
}

// ---------------------------------------------------------------------------
// kA: 128(t) x 256(d) output per block; grid (3, 16, gs). yKV tile =
//     QR[t-tile] @ H16[z][c-1]^T (K=256, skipped for c=0)
//   + sum_{j<=it} SB tile @ XT16 (K=128 each), c = tt/4, it = tt%4.
// ---------------------------------------------------------------------------
__global__ __launch_bounds__(256) void kA_attn(
    const u16* __restrict__ qr16, const u16* __restrict__ h16,
    const u16* __restrict__ sb, const u16* __restrict__ xt16,
    u16* __restrict__ ykv16, int bh0) {
  __shared__ __attribute__((aligned(16))) u16 smem[16384];
  u16* As = smem;          // 128 x 32
  u16* Bs = smem + 4096;   // 256 x 32 (two 128x32 panels)
  const int tid = threadIdx.x;
  const int w = tid >> 6, lane = tid & 63;
  const int wr = w >> 1, wc = w & 1;
  const int m16 = lane & 15, quad = lane >> 4;
  const int z = blockIdx.z;
  const int bh = bh0 + z, b = bh / NHH;
  const int tt = blockIdx.y;                 // global t-tile 0..15
  const int c = tt >> 2, it = tt & 3;
  const int d0 = blockIdx.x * 256;
  const int t0 = tt * 128;
  f32x4 acc[4][8];
#pragma unroll
  for (int i = 0; i < 4; ++i)
#pragma unroll
    for (int j = 0; j < 8; ++j) acc[i][j] = (f32x4){0.f, 0.f, 0.f, 0.f};

#define KA_STEP()                                                              \
  {                                                                            \
    bf16x8 a[4], bfr[8];                                                       \
    _Pragma("unroll") for (int i = 0; i < 4; ++i)                              \
        a[i] = *(const bf16x8*)&As[(wr * 64 + i * 16 + m16) * 32 + quad * 8];  \
    _Pragma("unroll") for (int j = 0; j < 8; ++j)                              \
        bfr[j] = *(const bf16x8*)&Bs[(wc * 128 + j * 16 + m16) * 32 + quad * 8];\
    _Pragma("unroll") for (int i = 0; i < 4; ++i)                              \
    _Pragma("unroll") for (int j = 0; j < 8; ++j)                              \
        acc[i][j] = __builtin_amdgcn_mfma_f32_16x16x32_bf16(a[i], bfr[j],      \
                                                            acc[i][j], 0, 0, 0);\
  }

  if (c > 0) {
    const u16* hs = h16 + ((size_t)(z * 3 + c - 1) * DD + d0) * NN;
    for (int k0 = 0; k0 < NN; k0 += 32) {
      stage128x32(qr16 + ((size_t)bh * TT + t0) * NN + k0, NN, As, tid);
      stage128x32(hs + k0, NN, Bs, tid);
      stage128x32(hs + (size_t)128 * NN + k0, NN, Bs + 4096, tid);
      __syncthreads();
      KA_STEP();
      __syncthreads();
    }
  }
  const u16* xb = xt16 + ((size_t)b * DD + d0) * TT + c * CH;
  for (int j = 0; j <= it; ++j) {
    for (int k0 = 0; k0 < 128; k0 += 32) {
      stage128x32(sb + ((size_t)z * TT + t0) * CH + j * 128 + k0, CH, As, tid);
      stage128x32(xb + j * 128 + k0, TT, Bs, tid);
      stage128x32(xb + (size_t)128 * TT + j * 128 + k0, TT, Bs + 4096, tid);
      __syncthreads();
      KA_STEP();
      __syncthreads();
    }
  }
#pragma unroll
  for (int p = 0; p < 2; ++p) {
    __syncthreads();
    if (wr == p) {
#pragma unroll
      for (int i = 0; i < 4; ++i)
#pragma unroll
        for (int j = 0; j < 8; ++j)
#pragma unroll
          for (int r = 0; r < 4; ++r) {
            const int lr = i * 16 + quad * 4 + r;
            smem[lr * 256 + wc * 128 + j * 16 + m16] = f2b(acc[i][j][r]);
          }
    }
    __syncthreads();
#pragma unroll
    for (int s = 0; s < 8; ++s) {
      const int off = (s * 256 + tid) * 8;
      const int row = off >> 8, col = off & 255;
      *(u16x8*)&ykv16[((size_t)z * TT + t0 + p * 64 + row) * DD + d0 + col] =
          *(const u16x8*)&smem[off];
    }
  }
#undef KA_STEP
}

// ---------------------------------------------------------------------------
// K3: per-row mean/rstd of group-local ykv16 (bf16 rows of 768). 1 wave/row.
// ---------------------------------------------------------------------------
__global__ __launch_bounds__(256) void k3_stats(
    const u16* __restrict__ ykv16, float* __restrict__ mu, float* __restrict__ rs) {
  const int row = blockIdx.x * 4 + (threadIdx.x >> 6);
  const int lane = threadIdx.x & 63;
  const u16* p = ykv16 + (size_t)row * DD;
  float sum = 0.f, sq = 0.f;
#pragma unroll
  for (int i = 0; i < 3; ++i) {
    ushort4 v = *(const ushort4*)&p[(lane << 2) + i * 256];
    float f0 = b2f(v.x), f1 = b2f(v.y), f2 = b2f(v.z), f3 = b2f(v.w);
    sum += f0 + f1 + f2 + f3;
    sq += f0 * f0 + f1 * f1 + f2 * f2 + f3 * f3;
  }
#pragma unroll
  for (int off = 32; off; off >>= 1) {
    sum += __shfl_xor(sum, off);
    sq += __shfl_xor(sq, off);
  }
  if (lane == 0) {
    float m = sum * (1.f / 768.f);
    float v = sq * (1.f / 768.f) - m * m;
    mu[row] = m;
    rs[row] = rsqrtf(v + 1e-5f);
  }
}

// ---------------------------------------------------------------------------
// K4: raw GEMM ykv16 @ ENCVT[h]^T with LN as epilogue affine; xs via inverse
// rope of QR16; out2 = xs*ys (fp32); XY (bf16) written IN PLACE into QR16's
// storage (reads of QR complete behind a barrier before the writes).
// ---------------------------------------------------------------------------
__global__ __launch_bounds__(256) void k4_xy(
    const u16* __restrict__ ykv16, const u16* __restrict__ encvt,
    u16* __restrict__ qrxy, const float* __restrict__ mu,
    const float* __restrict__ rs, const float* __restrict__ colsum,
    float* __restrict__ out2, int bh0) {
  const int z = blockIdx.z;
  const int bh = bh0 + z, h = bh % NHH;
  const int t0 = blockIdx.x * 128, n0 = blockIdx.y * 128;
  GEMM_PROLOGUE();
  for (int k0 = 0; k0 < DD; k0 += 32) {
    stage128x32(ykv16 + ((size_t)z * TT + t0) * DD + k0, DD, As, tid);
    stage128x32(encvt + ((size_t)h * NN + n0) * DD + k0, DD, Bs, tid);
    __syncthreads();
    mfma_step(As, Bs, wr, wc, lane, acc);
    __syncthreads();
  }
#pragma unroll
  for (int p = 0; p < 2; ++p) {
    __syncthreads();
    if (wr == p) {
#pragma unroll
      for (int i = 0; i < 4; ++i)
#pragma unroll
        for (int j = 0; j < 4; ++j) {
          const int n = n0 + wc * 64 + j * 16 + col16;
          const int qn = n & ~1;
          const float freq = exp2f((float)qn * -0.0625f) * 0.15915494309189535f;
          const float cs = colsum[h * NN + n];
#pragma unroll
          for (int r = 0; r < 4; ++r) {
            const int lr = i * 16 + quad * 4 + r;
            const int t = t0 + p * 64 + lr;
            const int lrow = z * TT + t;
            const float muv = mu[lrow], rsv = rs[lrow];
            float ys = fmaxf(rsv * acc[i][j][r] - rsv * muv * cs, 0.f);
            const size_t gi = ((size_t)bh * TT + t) * NN + n;
            float qs = b2f(qrxy[gi]);
            float qp = b2f(qrxy[gi ^ 1]);
            float phase = (float)t * freq;
            float ph = (phase - floorf(phase)) * 6.283185307179586f;
            float s = __sinf(ph), c2 = __cosf(ph);
            float xs = (n & 1) ? (qs * c2 - qp * s) : (qs * c2 + qp * s);
            float val = ys * xs;
            out2[gi] = val;
            smem[lr * 128 + wc * 64 + j * 16 + col16] = f2b(val);
          }
        }
    }
    __syncthreads();
    copy_out64(smem, qrxy + ((size_t)bh * TT + t0 + p * 64) * NN + n0, NN, tid);
  }
}

// ---------------------------------------------------------------------------
// K5: ymlp = flat(XY) @ DECT^T.  M=4096, N=768, K=3072.  64x64 tiles
// (768 blocks); A gathered from XY's [b][h][t][n] layout (in QR16 storage).
// ---------------------------------------------------------------------------
__global__ __launch_bounds__(256) void k5_mlp(
    const u16* __restrict__ xyq, const u16* __restrict__ dect,
    float* __restrict__ ymlp) {
  __shared__ __attribute__((aligned(16))) u16 sm[4096];
  u16* As = sm;
  u16* Bs = sm + 2048;
  const int tid = threadIdx.x;
  const int w = tid >> 6, lane = tid & 63;
  const int wr = w >> 1, wc = w & 1;
  const int m16 = lane & 15, quad = lane >> 4;
  const int m0 = blockIdx.x * 64, d0 = blockIdx.y * 64;
  f32x4 acc[2][2];
#pragma unroll
  for (int i = 0; i < 2; ++i)
#pragma unroll
    for (int j = 0; j < 2; ++j) acc[i][j] = (f32x4){0.f, 0.f, 0.f, 0.f};
  const int ar = w * 16 + (lane >> 2);      // A row within 64-tile
  const int m = m0 + ar;
  const int b = m >> 11, t = m & (TT - 1);
  const int kc = (lane & 3) << 3;
  for (int k0 = 0; k0 < NHH * NN; k0 += 32) {
    const int hh = k0 >> 8;
    const int kk = (k0 & 255) + kc;
    async16(xyq + ((size_t)(b * NHH + hh) * TT + t) * NN + kk, As + w * 512);
    stage64x32(dect + (size_t)d0 * (NHH * NN) + k0, NHH * NN, Bs, tid);
    __syncthreads();
    bf16x8 a[2], bb[2];
#pragma unroll
    for (int i = 0; i < 2; ++i)
      a[i] = *(const bf16x8*)&As[(wr * 32 + i * 16 + m16) * 32 + quad * 8];
#pragma unroll
    for (int j = 0; j < 2; ++j)
      bb[j] = *(const bf16x8*)&Bs[(wc * 32 + j * 16 + m16) * 32 + quad * 8];
#pragma unroll
    for (int i = 0; i < 2; ++i)
#pragma unroll
      for (int j = 0; j < 2; ++j)
        acc[i][j] = __builtin_amdgcn_mfma_f32_16x16x32_bf16(a[i], bb[j], acc[i][j], 0, 0, 0);
    __syncthreads();
  }
#pragma unroll
  for (int i = 0; i < 2; ++i)
#pragma unroll
    for (int j = 0; j < 2; ++j) {
      const int d = d0 + wc * 32 + j * 16 + m16;
#pragma unroll
      for (int r = 0; r < 4; ++r) {
        const int mm = m0 + wr * 32 + i * 16 + quad * 4 + r;
        ymlp[(size_t)mm * DD + d] = acc[i][j][r];
      }
    }
}

// ---------------------------------------------------------------------------
// K6: y = ln(ymlp)*sqrt(0.1/(ra+1e-6))*scale; out1 = ln(x+y). Block per row.
// ymlp aliases out1 (in-place per row).
// ---------------------------------------------------------------------------
__global__ __launch_bounds__(256) void k6_final(
    const float* __restrict__ ymlp, const float* __restrict__ x,
    const float* __restrict__ scale, const float* __restrict__ ra,
    float* __restrict__ out1) {
  const int row = blockIdx.x;
  const int tid = threadIdx.x;
  const int wid = tid >> 6, lane = tid & 63;
  __shared__ float red[8];
  float v[3];
  float sum = 0.f, sq = 0.f;
#pragma unroll
  for (int j = 0; j < 3; ++j) {
    v[j] = ymlp[(size_t)row * DD + tid + j * 256];
    sum += v[j]; sq += v[j] * v[j];
  }
#pragma unroll
  for (int off = 32; off; off >>= 1) { sum += __shfl_xor(sum, off); sq += __shfl_xor(sq, off); }
  if (lane == 0) { red[wid] = sum; red[4 + wid] = sq; }
  __syncthreads();
  sum = red[0] + red[1] + red[2] + red[3];
  sq = red[4] + red[5] + red[6] + red[7];
  const float m1 = sum * (1.f / 768.f);
  const float r1 = rsqrtf(sq * (1.f / 768.f) - m1 * m1 + 1e-5f);
  float z[3];
  float sum2 = 0.f, sq2 = 0.f;
#pragma unroll
  for (int j = 0; j < 3; ++j) {
    const int d = tid + j * 256;
    float y = (v[j] - m1) * r1 * sqrtf(0.1f / (ra[d] + 1e-6f)) * scale[d];
    z[j] = x[(size_t)row * DD + d] + y;
    sum2 += z[j]; sq2 += z[j] * z[j];
  }
  __syncthreads();
#pragma unroll
  for (int off = 32; off; off >>= 1) { sum2 += __shfl_xor(sum2, off); sq2 += __shfl_xor(sq2, off); }
  if (lane == 0) { red[wid] = sum2; red[4 + wid] = sq2; }
  __syncthreads();
  sum2 = red[0] + red[1] + red[2] + red[3];
  sq2 = red[4] + red[5] + red[6] + red[7];
  const float m2 = sum2 * (1.f / 768.f);
  const float r2 = rsqrtf(sq2 * (1.f / 768.f) - m2 * m2 + 1e-5f);
#pragma unroll
  for (int j = 0; j < 3; ++j)
    out1[(size_t)row * DD + tid + j * 256] = (z[j] - m2) * r2;
}

// ---------------------------------------------------------------------------
extern "C" void kernel_launch(void* const* d_in, const int* in_sizes, int n_in,
                              void* d_out, int out_size, void* d_ws, size_t ws_size,
                              hipStream_t stream) {
  const float* x = (const float*)d_in[0];
  const float* enc = (const float*)d_in[1];
  const float* encv = (const float*)d_in[2];
  const float* dec = (const float*)d_in[3];
  const float* scale = (const float*)d_in[4];
  const float* ra = (const float*)d_in[5];
  float* out1 = (float*)d_out;
  float* out2 = out1 + (size_t)BB * TT * DD;
  float* ymlp = out1;                         // k5 scratch, k6 in-place

  const int NS = BB * NHH;  // 24 slices
  unsigned char* p = (unsigned char*)d_ws;
  u16* X16 = (u16*)p;    p += (size_t)BB * TT * DD * 2;
  u16* XT16 = (u16*)p;   p += (size_t)BB * DD * TT * 2;
  u16* ENCT = (u16*)p;   p += (size_t)NHH * NN * DD * 2;
  u16* ENCVT = (u16*)p;  p += (size_t)NHH * NN * DD * 2;
  u16* DECT = (u16*)p;   p += (size_t)DD * NHH * NN * 2;
  u16* QR16 = (u16*)p;   p += (size_t)NS * TT * NN * 2;   // holds QR, then XY
  u16* QRT16 = (u16*)p;  p += (size_t)NS * NN * TT * 2;
  float* COLSUM = (float*)p; p += (size_t)NHH * NN * 4;
  // Adaptive, BALANCED per-slice attention pool:
  //   SB (TT*CH bf16) + H16 (3 snapshots DD*NN bf16) + YKV16 (TT*DD bf16)
  //   + MU/RS (TT f32 each)
  const size_t SLICE_B = (size_t)TT * CH * 2 + 3 * (size_t)DD * NN * 2 +
                         (size_t)TT * DD * 2 + (size_t)TT * 8;
  size_t fixed = (size_t)(p - (unsigned char*)d_ws);
  size_t rem = (ws_size > fixed) ? ws_size - fixed : 0;
  int GSmax = (int)(rem / SLICE_B);
  if (GSmax < 1) GSmax = 1;
  if (GSmax > NS) GSmax = NS;
  const int ngrp = (NS + GSmax - 1) / GSmax;
  const int GS = (NS + ngrp - 1) / ngrp;     // balanced groups
  u16* SB = (u16*)p;     p += (size_t)GS * TT * CH * 2;
  u16* H16 = (u16*)p;    p += (size_t)GS * 3 * DD * NN * 2;
  u16* YKV16 = (u16*)p;  p += (size_t)GS * TT * DD * 2;
  float* MU = (float*)p; p += (size_t)GS * TT * 4;
  float* RS = (float*)p; p += (size_t)GS * TT * 4;

  // One-time conversions / transposes
  cvt_bf16<<<dim3((BB * TT * DD) / 1024), 256, 0, stream>>>(x, X16, (size_t)BB * TT * DD / 4);
  tcvt_bf16<<<dim3(DD / 32, TT / 32, BB), 256, 0, stream>>>(
      x, XT16, TT, DD, (size_t)TT * DD, (size_t)DD * TT);
  tcvt_bf16<<<dim3(NN / 32, DD / 32, NHH), 256, 0, stream>>>(
      enc, ENCT, DD, NN, (size_t)DD * NN, (size_t)NN * DD);
  tcvt_bf16<<<dim3(NN / 32, DD / 32, NHH), 256, 0, stream>>>(
      encv, ENCVT, DD, NN, (size_t)DD * NN, (size_t)NN * DD);
  tcvt_bf16<<<dim3(DD / 32, (NHH * NN) / 32, 1), 256, 0, stream>>>(
      dec, DECT, NHH * NN, DD, 0, 0);
  k_colsum<<<dim3(NHH * NN / 4), 256, 0, stream>>>(ENCVT, COLSUM);

  k1_encode<<<dim3(BB * TT / 128, NN / 128, NHH), 256, 0, stream>>>(
      X16, ENCT, QR16, QRT16);

  for (int bh0 = 0; bh0 < NS; bh0 += GS) {
    const int gs = imin(GS, NS - bh0);
    kS_band<<<dim3(40, gs), 256, 0, stream>>>(QR16, SB, bh0);
    for (int c = 0; c < TT / CH - 1; ++c)
      kB_state<<<dim3(DD / 128, NN / 128, gs), 256, 0, stream>>>(
          XT16, QRT16, H16, c, bh0);
    kA_attn<<<dim3(DD / 256, TT / 128, gs), 256, 0, stream>>>(
        QR16, H16, SB, XT16, YKV16, bh0);
    k3_stats<<<dim3(gs * TT / 4), 256, 0, stream>>>(YKV16, MU, RS);
    k4_xy<<<dim3(TT / 128, NN / 128, gs), 256, 0, stream>>>(
        YKV16, ENCVT, QR16, MU, RS, COLSUM, out2, bh0);
  }

  k5_mlp<<<dim3(BB * TT / 64, DD / 64), 256, 0, stream>>>(QR16, DECT, ymlp);
  k6_final<<<dim3(BB * TT), 256, 0, stream>>>(ymlp, x, scale, ra, out1);
}

// Round 9
// 483.971 us; speedup vs baseline: 1.3790x; 1.1056x over previous
//
#include <hip/hip_runtime.h>
#include <math.h>

#define TT 2048
#define DD 768
#define NN 256
#define NHH 12
#define BB 2
#define CH 512           // attention chunk (4 chunks of 4 x 128-tiles)

typedef unsigned short u16;
typedef __attribute__((ext_vector_type(8))) short bf16x8;
typedef __attribute__((ext_vector_type(8))) unsigned short u16x8;
typedef __attribute__((ext_vector_type(4))) float f32x4;

static inline int imin(int a, int b) { return a < b ? a : b; }

__device__ __forceinline__ u16 f2b(float f) {
  union { float f; unsigned u; } a; a.f = f;
  unsigned r = a.u + 0x7FFF + ((a.u >> 16) & 1);
  return (u16)(r >> 16);
}
__device__ __forceinline__ float b2f(u16 h) {
  union { unsigned u; float f; } a; a.u = ((unsigned)h) << 16;
  return a.f;
}

__device__ __forceinline__ void async16(const void* g, void* l) {
  __builtin_amdgcn_global_load_lds(
      (const __attribute__((address_space(1))) unsigned*)g,
      (__attribute__((address_space(3))) unsigned*)l, 16, 0, 0);
}

// Stage a 128x32 bf16 tile (row-major, ld in elements) into LDS [128][32].
__device__ __forceinline__ void stage128x32(
    const u16* __restrict__ gbase, size_t ld, u16* lds, int tid) {
  const int w = tid >> 6, l = tid & 63;
  const int r = l >> 2, kc = (l & 3) << 3;
#pragma unroll
  for (int q = 0; q < 2; ++q) {
    const int row0 = w * 32 + q * 16;
    async16(gbase + (size_t)(row0 + r) * ld + kc, lds + row0 * 32);
  }
}

// Stage a 64x32 bf16 tile into LDS [64][32]. One async16 per thread.
__device__ __forceinline__ void stage64x32(
    const u16* __restrict__ gbase, size_t ld, u16* lds, int tid) {
  const int w = tid >> 6, l = tid & 63;
  const int r = w * 16 + (l >> 2), kc = (l & 3) << 3;
  async16(gbase + (size_t)r * ld + kc, lds + w * 512);
}

// 16 MFMAs of one BK=32 step; wave (wr,wc) computes 64x64 of the 128x128 tile.
__device__ __forceinline__ void mfma_step(
    const u16* As, const u16* Bs, int wr, int wc, int lane, f32x4 acc[4][4]) {
  const int m16 = lane & 15, quad = lane >> 4;
  bf16x8 a[4], b[4];
#pragma unroll
  for (int i = 0; i < 4; ++i)
    a[i] = *(const bf16x8*)&As[(wr * 64 + i * 16 + m16) * 32 + quad * 8];
#pragma unroll
  for (int j = 0; j < 4; ++j)
    b[j] = *(const bf16x8*)&Bs[(wc * 64 + j * 16 + m16) * 32 + quad * 8];
#pragma unroll
  for (int i = 0; i < 4; ++i)
#pragma unroll
    for (int j = 0; j < 4; ++j)
      acc[i][j] = __builtin_amdgcn_mfma_f32_16x16x32_bf16(a[i], b[j], acc[i][j], 0, 0, 0);
}

// copy a 64x128 u16 tile from LDS (row-major, no pad) to global rows of ld.
__device__ __forceinline__ void copy_out64(
    const u16* buf, u16* g, size_t ld, int tid) {
#pragma unroll
  for (int s = 0; s < 4; ++s) {
    const int off = (s * 256 + tid) * 8;
    const int row = off >> 7, col = off & 127;
    *(u16x8*)&g[(size_t)row * ld + col] = *(const u16x8*)&buf[off];
  }
}

#define GEMM_PROLOGUE()                                            \
  __shared__ __attribute__((aligned(16))) u16 smem[8192];          \
  u16* As = smem;                                                  \
  u16* Bs = smem + 4096;                                           \
  const int tid = threadIdx.x;                                     \
  const int w = tid >> 6, lane = tid & 63;                         \
  const int wr = w >> 1, wc = w & 1;                               \
  const int col16 = lane & 15, quad = lane >> 4;                   \
  f32x4 acc[4][4];                                                 \
  _Pragma("unroll") for (int i = 0; i < 4; ++i)                    \
  _Pragma("unroll") for (int j = 0; j < 4; ++j)                    \
      acc[i][j] = (f32x4){0.f, 0.f, 0.f, 0.f};

// ---------------------------------------------------------------------------
__global__ __launch_bounds__(256) void cvt_bf16(
    const float* __restrict__ in, u16* __restrict__ out, size_t n4) {
  size_t i = ((size_t)blockIdx.x * 256 + threadIdx.x) * 4;
  if (i >= n4 * 4) return;
  float4 v = *(const float4*)&in[i];
  u16 o[4] = {f2b(v.x), f2b(v.y), f2b(v.z), f2b(v.w)};
  *(ushort4*)&out[i] = *(ushort4*)o;
}

__global__ __launch_bounds__(256) void tcvt_bf16(
    const float* __restrict__ in, u16* __restrict__ out, int R, int C,
    size_t inStride, size_t outStride) {
  __shared__ float tile[32][33];
  const float* ip = in + (size_t)blockIdx.z * inStride;
  u16* op = out + (size_t)blockIdx.z * outStride;
  const int c0 = blockIdx.x * 32, r0 = blockIdx.y * 32;
  const int tx = threadIdx.x & 31, ty = threadIdx.x >> 5;
#pragma unroll
  for (int p = 0; p < 4; ++p)
    tile[ty + p * 8][tx] = ip[(size_t)(r0 + ty + p * 8) * C + c0 + tx];
  __syncthreads();
#pragma unroll
  for (int p = 0; p < 4; ++p)
    op[(size_t)(c0 + ty + p * 8) * R + r0 + tx] = f2b(tile[tx][ty + p * 8]);
}

__global__ __launch_bounds__(256) void k_colsum(
    const u16* __restrict__ encvt, float* __restrict__ colsum) {
  const int row = blockIdx.x * 4 + (threadIdx.x >> 6);
  const int lane = threadIdx.x & 63;
  const u16* pr = encvt + (size_t)row * DD;
  float s = 0.f;
#pragma unroll
  for (int i = 0; i < 3; ++i) {
    ushort4 v = *(const ushort4*)&pr[(lane << 2) + i * 256];
    s += b2f(v.x) + b2f(v.y) + b2f(v.z) + b2f(v.w);
  }
#pragma unroll
  for (int off = 32; off; off >>= 1) s += __shfl_xor(s, off);
  if (lane == 0) colsum[row] = s;
}

// ---------------------------------------------------------------------------
// K1: latent = X16 @ ENCT[h]^T; relu; rope -> QR16 [b][h][t][n] AND
// QRT16 [b][h][n][t].  M=4096, N=256, K=768 per head.
// ---------------------------------------------------------------------------
__global__ __launch_bounds__(256) void k1_encode(
    const u16* __restrict__ x16, const u16* __restrict__ enct,
    u16* __restrict__ qr16, u16* __restrict__ qrt16) {
  const int h = blockIdx.z;
  const int m0 = blockIdx.x * 128, n0 = blockIdx.y * 128;
  GEMM_PROLOGUE();
  for (int k0 = 0; k0 < DD; k0 += 32) {
    stage128x32(x16 + (size_t)m0 * DD + k0, DD, As, tid);
    stage128x32(enct + ((size_t)h * NN + n0) * DD + k0, DD, Bs, tid);
    __syncthreads();
    mfma_step(As, Bs, wr, wc, lane, acc);
    __syncthreads();
  }
#pragma unroll
  for (int p = 0; p < 2; ++p) {
    __syncthreads();
    if (wr == p) {
#pragma unroll
      for (int i = 0; i < 4; ++i)
#pragma unroll
        for (int j = 0; j < 4; ++j) {
          const int n = n0 + wc * 64 + j * 16 + col16;
          const int q = n & ~1;
          const float freq = exp2f((float)q * -0.0625f) * 0.15915494309189535f;
          float rv[4], pv[4];
#pragma unroll
          for (int r = 0; r < 4; ++r) rv[r] = fmaxf(acc[i][j][r], 0.f);
#pragma unroll
          for (int r = 0; r < 4; ++r) pv[r] = __shfl_xor(rv[r], 1);
#pragma unroll
          for (int r = 0; r < 4; ++r) {
            const int lr = i * 16 + quad * 4 + r;
            const int t = (m0 + p * 64 + lr) & (TT - 1);
            float phase = (float)t * freq;
            float ph = (phase - floorf(phase)) * 6.283185307179586f;
            float s = __sinf(ph), c = __cosf(ph);
            float o = (n & 1) ? (rv[r] * c + pv[r] * s) : (rv[r] * c - pv[r] * s);
            smem[lr * 128 + wc * 64 + j * 16 + col16] = f2b(o);
          }
        }
    }
    __syncthreads();
    const int m = m0 + p * 64;
    const int b = m >> 11, tb = m & (TT - 1);
    const size_t sl = (size_t)(b * NHH + h);
    copy_out64(smem, qr16 + (sl * TT + tb) * NN + n0, NN, tid);
    // transposed copy: QRT16[sl][n][t] = tile[t][n]
#pragma unroll
    for (int s = 0; s < 4; ++s) {
      const int off = (s * 256 + tid) * 8;
      const int nr = off >> 6, tc = off & 63;
      u16 vals[8];
#pragma unroll
      for (int k = 0; k < 8; ++k) vals[k] = smem[(tc + k) * 128 + nr];
      *(u16x8*)&qrt16[(sl * NN + n0 + nr) * TT + tb + tc] = *(u16x8*)vals;
    }
  }
}

// ---------------------------------------------------------------------------
// kS: block-diagonal band of S = QR QR^T (strict lower), 40 tiles/slice.
// SB (group-local) [gs][TT][CH], sc = s - 512*(t/512).
// ---------------------------------------------------------------------------
__global__ __launch_bounds__(256) void kS_band(
    const u16* __restrict__ qr16, u16* __restrict__ sb, int bh0) {
  const int z = blockIdx.y;                  // group-local slice
  const int bh = bh0 + z;
  const int cc = blockIdx.x / 10, rr = blockIdx.x % 10;
  int i = (int)((sqrtf(8.f * rr + 1.f) - 1.f) * 0.5f);
  while ((i + 1) * (i + 2) / 2 <= rr) ++i;
  while (i * (i + 1) / 2 > rr) --i;
  const int j = rr - i * (i + 1) / 2;
  const int t0 = (cc * 4 + i) * 128;
  const int s0 = cc * CH + j * 128;
  const u16* q = qr16 + (size_t)bh * TT * NN;
  GEMM_PROLOGUE();
  for (int k0 = 0; k0 < NN; k0 += 32) {
    stage128x32(q + (size_t)t0 * NN + k0, NN, As, tid);
    stage128x32(q + (size_t)s0 * NN + k0, NN, Bs, tid);
    __syncthreads();
    mfma_step(As, Bs, wr, wc, lane, acc);
    __syncthreads();
  }
  const bool diag = (i == j);
#pragma unroll
  for (int p = 0; p < 2; ++p) {
    __syncthreads();
    if (wr == p) {
#pragma unroll
      for (int ii = 0; ii < 4; ++ii)
#pragma unroll
        for (int jj = 0; jj < 4; ++jj) {
          const int s = s0 + wc * 64 + jj * 16 + col16;
#pragma unroll
          for (int r = 0; r < 4; ++r) {
            const int lr = ii * 16 + quad * 4 + r;
            const int t = t0 + p * 64 + lr;
            float v = acc[ii][jj][r];
            if (diag && s >= t) v = 0.f;
            smem[lr * 128 + wc * 64 + jj * 16 + col16] = f2b(v);
          }
        }
    }
    __syncthreads();
    copy_out64(smem, sb + ((size_t)z * TT + t0 + p * 64) * CH + j * 128, CH, tid);
  }
}

// ---------------------------------------------------------------------------
// kB_all: ONE launch. Each block owns a 64(d) x 128(n) tile of H and runs
// K = 0..1536 with fp32 accumulators, writing bf16 snapshot H16[z][c] at each
// chunk boundary (c = 0,1,2). Grid (12, 2, gs).
// ---------------------------------------------------------------------------
__global__ __launch_bounds__(256) void kB_all(
    const u16* __restrict__ xt16, const u16* __restrict__ qrt16,
    u16* __restrict__ h16, int bh0) {
  __shared__ __attribute__((aligned(16))) u16 sm[8192];
  u16* As = sm;          // 64 x 32
  u16* Bs = sm + 2048;   // 128 x 32
  const int tid = threadIdx.x;
  const int w = tid >> 6, lane = tid & 63;
  const int m16 = lane & 15, quad = lane >> 4;
  const int z = blockIdx.z;
  const int bh = bh0 + z, b = bh / NHH;
  const int d0 = blockIdx.x * 64, n0 = blockIdx.y * 128;
  f32x4 acc[4][2];
#pragma unroll
  for (int i = 0; i < 4; ++i)
#pragma unroll
    for (int j = 0; j < 2; ++j) acc[i][j] = (f32x4){0.f, 0.f, 0.f, 0.f};
  const u16* Ab = xt16 + ((size_t)b * DD + d0) * TT;
  const u16* Bb = qrt16 + ((size_t)bh * NN + n0) * TT;
  for (int c = 0; c < 3; ++c) {
    for (int k0 = c * CH; k0 < (c + 1) * CH; k0 += 32) {
      stage64x32(Ab + k0, TT, As, tid);
      stage128x32(Bb + k0, TT, Bs, tid);
      __syncthreads();
      bf16x8 a[4], bb[2];
#pragma unroll
      for (int i = 0; i < 4; ++i)
        a[i] = *(const bf16x8*)&As[(i * 16 + m16) * 32 + quad * 8];
#pragma unroll
      for (int j = 0; j < 2; ++j)
        bb[j] = *(const bf16x8*)&Bs[(w * 32 + j * 16 + m16) * 32 + quad * 8];
#pragma unroll
      for (int i = 0; i < 4; ++i)
#pragma unroll
        for (int j = 0; j < 2; ++j)
          acc[i][j] = __builtin_amdgcn_mfma_f32_16x16x32_bf16(a[i], bb[j], acc[i][j], 0, 0, 0);
      __syncthreads();
    }
    // snapshot H16[z][c]: restage 64x128 fp32->bf16 via LDS, coalesced store
#pragma unroll
    for (int i = 0; i < 4; ++i)
#pragma unroll
      for (int j = 0; j < 2; ++j)
#pragma unroll
        for (int r = 0; r < 4; ++r)
          sm[(i * 16 + quad * 4 + r) * 128 + w * 32 + j * 16 + m16] =
              f2b(acc[i][j][r]);
    __syncthreads();
    u16* hd = h16 + (size_t)(z * 3 + c) * DD * NN;
#pragma unroll
    for (int s = 0; s < 4; ++s) {
      const int off = (s * 256 + tid) * 8;
      const int row = off >> 7, col = off & 127;
      *(u16x8*)&hd[(size_t)(d0 + row) * NN + n0 + col] = *(const u16x8*)&sm[off];
    }
    __syncthreads();
  }
}

// ---------------------------------------------------------------------------
// kA: 128x128 output, BK=64 (two 32-panels per barrier-pair). yKV tile =
//     QR[t-tile] @ H16[z][c-1]^T (K=256, skipped for c=0)
//   + sum_{j<=it} SB tile @ XT16 (K=128 each), c = tt/4, it = tt%4.
// Grid (6, 16, gs).
// ---------------------------------------------------------------------------
__global__ __launch_bounds__(256) void kA_attn(
    const u16* __restrict__ qr16, const u16* __restrict__ h16,
    const u16* __restrict__ sb, const u16* __restrict__ xt16,
    u16* __restrict__ ykv16, int bh0) {
  __shared__ __attribute__((aligned(16))) u16 smem[16384];
  u16* As = smem;          // 128 x 64 (two 128x32 panels)
  u16* Bs = smem + 8192;   // 128 x 64
  const int tid = threadIdx.x;
  const int w = tid >> 6, lane = tid & 63;
  const int wr = w >> 1, wc = w & 1;
  const int col16 = lane & 15, quad = lane >> 4;
  const int z = blockIdx.z;
  const int bh = bh0 + z, b = bh / NHH;
  const int tt = blockIdx.y;                 // global t-tile 0..15
  const int c = tt >> 2, it = tt & 3;
  const int d0 = blockIdx.x * 128;
  const int t0 = tt * 128;
  f32x4 acc[4][4];
#pragma unroll
  for (int i = 0; i < 4; ++i)
#pragma unroll
    for (int j = 0; j < 4; ++j) acc[i][j] = (f32x4){0.f, 0.f, 0.f, 0.f};

  if (c > 0) {
    const u16* hs = h16 + ((size_t)(z * 3 + c - 1) * DD + d0) * NN;
    const u16* qb = qr16 + ((size_t)bh * TT + t0) * NN;
    for (int k0 = 0; k0 < NN; k0 += 64) {
      stage128x32(qb + k0, NN, As, tid);
      stage128x32(qb + k0 + 32, NN, As + 4096, tid);
      stage128x32(hs + k0, NN, Bs, tid);
      stage128x32(hs + k0 + 32, NN, Bs + 4096, tid);
      __syncthreads();
      mfma_step(As, Bs, wr, wc, lane, acc);
      mfma_step(As + 4096, Bs + 4096, wr, wc, lane, acc);
      __syncthreads();
    }
  }
  const u16* sbb = sb + ((size_t)z * TT + t0) * CH;
  const u16* xb = xt16 + ((size_t)b * DD + d0) * TT + c * CH;
  for (int j = 0; j <= it; ++j) {
#pragma unroll
    for (int k0 = 0; k0 < 128; k0 += 64) {
      stage128x32(sbb + j * 128 + k0, CH, As, tid);
      stage128x32(sbb + j * 128 + k0 + 32, CH, As + 4096, tid);
      stage128x32(xb + j * 128 + k0, TT, Bs, tid);
      stage128x32(xb + j * 128 + k0 + 32, TT, Bs + 4096, tid);
      __syncthreads();
      mfma_step(As, Bs, wr, wc, lane, acc);
      mfma_step(As + 4096, Bs + 4096, wr, wc, lane, acc);
      __syncthreads();
    }
  }
#pragma unroll
  for (int p = 0; p < 2; ++p) {
    __syncthreads();
    if (wr == p) {
#pragma unroll
      for (int i = 0; i < 4; ++i)
#pragma unroll
        for (int j = 0; j < 4; ++j)
#pragma unroll
          for (int r = 0; r < 4; ++r) {
            const int lr = i * 16 + quad * 4 + r;
            smem[lr * 128 + wc * 64 + j * 16 + col16] = f2b(acc[i][j][r]);
          }
    }
    __syncthreads();
    copy_out64(smem, ykv16 + ((size_t)z * TT + t0 + p * 64) * DD + d0, DD, tid);
  }
}

// ---------------------------------------------------------------------------
// K3: per-row mean/rstd of group-local ykv16 (bf16 rows of 768). 1 wave/row.
// ---------------------------------------------------------------------------
__global__ __launch_bounds__(256) void k3_stats(
    const u16* __restrict__ ykv16, float* __restrict__ mu, float* __restrict__ rs) {
  const int row = blockIdx.x * 4 + (threadIdx.x >> 6);
  const int lane = threadIdx.x & 63;
  const u16* p = ykv16 + (size_t)row * DD;
  float sum = 0.f, sq = 0.f;
#pragma unroll
  for (int i = 0; i < 3; ++i) {
    ushort4 v = *(const ushort4*)&p[(lane << 2) + i * 256];
    float f0 = b2f(v.x), f1 = b2f(v.y), f2 = b2f(v.z), f3 = b2f(v.w);
    sum += f0 + f1 + f2 + f3;
    sq += f0 * f0 + f1 * f1 + f2 * f2 + f3 * f3;
  }
#pragma unroll
  for (int off = 32; off; off >>= 1) {
    sum += __shfl_xor(sum, off);
    sq += __shfl_xor(sq, off);
  }
  if (lane == 0) {
    float m = sum * (1.f / 768.f);
    float v = sq * (1.f / 768.f) - m * m;
    mu[row] = m;
    rs[row] = rsqrtf(v + 1e-5f);
  }
}

// ---------------------------------------------------------------------------
// K4: raw GEMM ykv16 @ ENCVT[h]^T with LN as epilogue affine; xs via inverse
// rope of QR16; out2 = xs*ys (fp32); XY (bf16) written IN PLACE into QR16's
// storage (reads of QR complete behind a barrier before the writes).
// ---------------------------------------------------------------------------
__global__ __launch_bounds__(256) void k4_xy(
    const u16* __restrict__ ykv16, const u16* __restrict__ encvt,
    u16* __restrict__ qrxy, const float* __restrict__ mu,
    const float* __restrict__ rs, const float* __restrict__ colsum,
    float* __restrict__ out2, int bh0) {
  const int z = blockIdx.z;
  const int bh = bh0 + z, h = bh % NHH;
  const int t0 = blockIdx.x * 128, n0 = blockIdx.y * 128;
  GEMM_PROLOGUE();
  for (int k0 = 0; k0 < DD; k0 += 32) {
    stage128x32(ykv16 + ((size_t)z * TT + t0) * DD + k0, DD, As, tid);
    stage128x32(encvt + ((size_t)h * NN + n0) * DD + k0, DD, Bs, tid);
    __syncthreads();
    mfma_step(As, Bs, wr, wc, lane, acc);
    __syncthreads();
  }
#pragma unroll
  for (int p = 0; p < 2; ++p) {
    __syncthreads();
    if (wr == p) {
#pragma unroll
      for (int i = 0; i < 4; ++i)
#pragma unroll
        for (int j = 0; j < 4; ++j) {
          const int n = n0 + wc * 64 + j * 16 + col16;
          const int qn = n & ~1;
          const float freq = exp2f((float)qn * -0.0625f) * 0.15915494309189535f;
          const float cs = colsum[h * NN + n];
#pragma unroll
          for (int r = 0; r < 4; ++r) {
            const int lr = i * 16 + quad * 4 + r;
            const int t = t0 + p * 64 + lr;
            const int lrow = z * TT + t;
            const float muv = mu[lrow], rsv = rs[lrow];
            float ys = fmaxf(rsv * acc[i][j][r] - rsv * muv * cs, 0.f);
            const size_t gi = ((size_t)bh * TT + t) * NN + n;
            float qs = b2f(qrxy[gi]);
            float qp = b2f(qrxy[gi ^ 1]);
            float phase = (float)t * freq;
            float ph = (phase - floorf(phase)) * 6.283185307179586f;
            float s = __sinf(ph), c2 = __cosf(ph);
            float xs = (n & 1) ? (qs * c2 - qp * s) : (qs * c2 + qp * s);
            float val = ys * xs;
            out2[gi] = val;
            smem[lr * 128 + wc * 64 + j * 16 + col16] = f2b(val);
          }
        }
    }
    __syncthreads();
    copy_out64(smem, qrxy + ((size_t)bh * TT + t0 + p * 64) * NN + n0, NN, tid);
  }
}

// ---------------------------------------------------------------------------
// K5: ymlp = flat(XY) @ DECT^T.  M=4096, N=768, K=3072.  64x64 tiles
// (768 blocks); A gathered from XY's [b][h][t][n] layout (in QR16 storage).
// ---------------------------------------------------------------------------
__global__ __launch_bounds__(256) void k5_mlp(
    const u16* __restrict__ xyq, const u16* __restrict__ dect,
    float* __restrict__ ymlp) {
  __shared__ __attribute__((aligned(16))) u16 sm[4096];
  u16* As = sm;
  u16* Bs = sm + 2048;
  const int tid = threadIdx.x;
  const int w = tid >> 6, lane = tid & 63;
  const int wr = w >> 1, wc = w & 1;
  const int m16 = lane & 15, quad = lane >> 4;
  const int m0 = blockIdx.x * 64, d0 = blockIdx.y * 64;
  f32x4 acc[2][2];
#pragma unroll
  for (int i = 0; i < 2; ++i)
#pragma unroll
    for (int j = 0; j < 2; ++j) acc[i][j] = (f32x4){0.f, 0.f, 0.f, 0.f};
  const int ar = w * 16 + (lane >> 2);      // A row within 64-tile
  const int m = m0 + ar;
  const int b = m >> 11, t = m & (TT - 1);
  const int kc = (lane & 3) << 3;
  for (int k0 = 0; k0 < NHH * NN; k0 += 32) {
    const int hh = k0 >> 8;
    const int kk = (k0 & 255) + kc;
    async16(xyq + ((size_t)(b * NHH + hh) * TT + t) * NN + kk, As + w * 512);
    stage64x32(dect + (size_t)d0 * (NHH * NN) + k0, NHH * NN, Bs, tid);
    __syncthreads();
    bf16x8 a[2], bb[2];
#pragma unroll
    for (int i = 0; i < 2; ++i)
      a[i] = *(const bf16x8*)&As[(wr * 32 + i * 16 + m16) * 32 + quad * 8];
#pragma unroll
    for (int j = 0; j < 2; ++j)
      bb[j] = *(const bf16x8*)&Bs[(wc * 32 + j * 16 + m16) * 32 + quad * 8];
#pragma unroll
    for (int i = 0; i < 2; ++i)
#pragma unroll
      for (int j = 0; j < 2; ++j)
        acc[i][j] = __builtin_amdgcn_mfma_f32_16x16x32_bf16(a[i], bb[j], acc[i][j], 0, 0, 0);
    __syncthreads();
  }
#pragma unroll
  for (int i = 0; i < 2; ++i)
#pragma unroll
    for (int j = 0; j < 2; ++j) {
      const int d = d0 + wc * 32 + j * 16 + m16;
#pragma unroll
      for (int r = 0; r < 4; ++r) {
        const int mm = m0 + wr * 32 + i * 16 + quad * 4 + r;
        ymlp[(size_t)mm * DD + d] = acc[i][j][r];
      }
    }
}

// ---------------------------------------------------------------------------
// K6: y = ln(ymlp)*sqrt(0.1/(ra+1e-6))*scale; out1 = ln(x+y). Block per row.
// ymlp aliases out1 (in-place per row).
// ---------------------------------------------------------------------------
__global__ __launch_bounds__(256) void k6_final(
    const float* __restrict__ ymlp, const float* __restrict__ x,
    const float* __restrict__ scale, const float* __restrict__ ra,
    float* __restrict__ out1) {
  const int row = blockIdx.x;
  const int tid = threadIdx.x;
  const int wid = tid >> 6, lane = tid & 63;
  __shared__ float red[8];
  float v[3];
  float sum = 0.f, sq = 0.f;
#pragma unroll
  for (int j = 0; j < 3; ++j) {
    v[j] = ymlp[(size_t)row * DD + tid + j * 256];
    sum += v[j]; sq += v[j] * v[j];
  }
#pragma unroll
  for (int off = 32; off; off >>= 1) { sum += __shfl_xor(sum, off); sq += __shfl_xor(sq, off); }
  if (lane == 0) { red[wid] = sum; red[4 + wid] = sq; }
  __syncthreads();
  sum = red[0] + red[1] + red[2] + red[3];
  sq = red[4] + red[5] + red[6] + red[7];
  const float m1 = sum * (1.f / 768.f);
  const float r1 = rsqrtf(sq * (1.f / 768.f) - m1 * m1 + 1e-5f);
  float z[3];
  float sum2 = 0.f, sq2 = 0.f;
#pragma unroll
  for (int j = 0; j < 3; ++j) {
    const int d = tid + j * 256;
    float y = (v[j] - m1) * r1 * sqrtf(0.1f / (ra[d] + 1e-6f)) * scale[d];
    z[j] = x[(size_t)row * DD + d] + y;
    sum2 += z[j]; sq2 += z[j] * z[j];
  }
  __syncthreads();
#pragma unroll
  for (int off = 32; off; off >>= 1) { sum2 += __shfl_xor(sum2, off); sq2 += __shfl_xor(sq2, off); }
  if (lane == 0) { red[wid] = sum2; red[4 + wid] = sq2; }
  __syncthreads();
  sum2 = red[0] + red[1] + red[2] + red[3];
  sq2 = red[4] + red[5] + red[6] + red[7];
  const float m2 = sum2 * (1.f / 768.f);
  const float r2 = rsqrtf(sq2 * (1.f / 768.f) - m2 * m2 + 1e-5f);
#pragma unroll
  for (int j = 0; j < 3; ++j)
    out1[(size_t)row * DD + tid + j * 256] = (z[j] - m2) * r2;
}

// ---------------------------------------------------------------------------
extern "C" void kernel_launch(void* const* d_in, const int* in_sizes, int n_in,
                              void* d_out, int out_size, void* d_ws, size_t ws_size,
                              hipStream_t stream) {
  const float* x = (const float*)d_in[0];
  const float* enc = (const float*)d_in[1];
  const float* encv = (const float*)d_in[2];
  const float* dec = (const float*)d_in[3];
  const float* scale = (const float*)d_in[4];
  const float* ra = (const float*)d_in[5];
  float* out1 = (float*)d_out;
  float* out2 = out1 + (size_t)BB * TT * DD;
  float* ymlp = out1;                         // k5 scratch, k6 in-place

  const int NS = BB * NHH;  // 24 slices
  unsigned char* p = (unsigned char*)d_ws;
  u16* X16 = (u16*)p;    p += (size_t)BB * TT * DD * 2;
  u16* XT16 = (u16*)p;   p += (size_t)BB * DD * TT * 2;
  u16* ENCT = (u16*)p;   p += (size_t)NHH * NN * DD * 2;
  u16* ENCVT = (u16*)p;  p += (size_t)NHH * NN * DD * 2;
  u16* DECT = (u16*)p;   p += (size_t)DD * NHH * NN * 2;
  u16* QR16 = (u16*)p;   p += (size_t)NS * TT * NN * 2;   // holds QR, then XY
  u16* QRT16 = (u16*)p;  p += (size_t)NS * NN * TT * 2;
  float* COLSUM = (float*)p; p += (size_t)NHH * NN * 4;
  // Adaptive, BALANCED per-slice attention pool:
  //   SB (TT*CH bf16) + H16 (3 snapshots DD*NN bf16) + YKV16 (TT*DD bf16)
  //   + MU/RS (TT f32 each)
  const size_t SLICE_B = (size_t)TT * CH * 2 + 3 * (size_t)DD * NN * 2 +
                         (size_t)TT * DD * 2 + (size_t)TT * 8;
  size_t fixed = (size_t)(p - (unsigned char*)d_ws);
  size_t rem = (ws_size > fixed) ? ws_size - fixed : 0;
  int GSmax = (int)(rem / SLICE_B);
  if (GSmax < 1) GSmax = 1;
  if (GSmax > NS) GSmax = NS;
  const int ngrp = (NS + GSmax - 1) / GSmax;
  const int GS = (NS + ngrp - 1) / ngrp;     // balanced groups
  u16* SB = (u16*)p;     p += (size_t)GS * TT * CH * 2;
  u16* H16 = (u16*)p;    p += (size_t)GS * 3 * DD * NN * 2;
  u16* YKV16 = (u16*)p;  p += (size_t)GS * TT * DD * 2;
  float* MU = (float*)p; p += (size_t)GS * TT * 4;
  float* RS = (float*)p; p += (size_t)GS * TT * 4;

  // One-time conversions / transposes
  cvt_bf16<<<dim3((BB * TT * DD) / 1024), 256, 0, stream>>>(x, X16, (size_t)BB * TT * DD / 4);
  tcvt_bf16<<<dim3(DD / 32, TT / 32, BB), 256, 0, stream>>>(
      x, XT16, TT, DD, (size_t)TT * DD, (size_t)DD * TT);
  tcvt_bf16<<<dim3(NN / 32, DD / 32, NHH), 256, 0, stream>>>(
      enc, ENCT, DD, NN, (size_t)DD * NN, (size_t)NN * DD);
  tcvt_bf16<<<dim3(NN / 32, DD / 32, NHH), 256, 0, stream>>>(
      encv, ENCVT, DD, NN, (size_t)DD * NN, (size_t)NN * DD);
  tcvt_bf16<<<dim3(DD / 32, (NHH * NN) / 32, 1), 256, 0, stream>>>(
      dec, DECT, NHH * NN, DD, 0, 0);
  k_colsum<<<dim3(NHH * NN / 4), 256, 0, stream>>>(ENCVT, COLSUM);

  k1_encode<<<dim3(BB * TT / 128, NN / 128, NHH), 256, 0, stream>>>(
      X16, ENCT, QR16, QRT16);

  for (int bh0 = 0; bh0 < NS; bh0 += GS) {
    const int gs = imin(GS, NS - bh0);
    kS_band<<<dim3(40, gs), 256, 0, stream>>>(QR16, SB, bh0);
    kB_all<<<dim3(DD / 64, NN / 128, gs), 256, 0, stream>>>(
        XT16, QRT16, H16, bh0);
    kA_attn<<<dim3(DD / 128, TT / 128, gs), 256, 0, stream>>>(
        QR16, H16, SB, XT16, YKV16, bh0);
    k3_stats<<<dim3(gs * TT / 4), 256, 0, stream>>>(YKV16, MU, RS);
    k4_xy<<<dim3(TT / 128, NN / 128, gs), 256, 0, stream>>>(
        YKV16, ENCVT, QR16, MU, RS, COLSUM, out2, bh0);
  }

  k5_mlp<<<dim3(BB * TT / 64, DD / 64), 256, 0, stream>>>(QR16, DECT, ymlp);
  k6_final<<<dim3(BB * TT), 256, 0, stream>>>(ymlp, x, scale, ra, out1);
}